// Round 1
// baseline (2293.552 us; speedup 1.0000x reference)
//
#include <hip/hip_runtime.h>

#define B 4096
#define J 16
#define HID 128
#define INTER 64
#define NLAYERS 4
#define NEGV -9000000000000000.0f
#define NROWS (B*J)          // 65536
#define ELEMS ((size_t)NROWS*HID)  // 8388608

// ---------------------------------------------------------------- adjacency
// 10 matrices: m=0 gc_in, m=1..8 e_res rows, m=9 gc_out.
__global__ void adj_kernel(const float* __restrict__ e_in,
                           const float* __restrict__ e_res,
                           const float* __restrict__ e_out,
                           const int* __restrict__ rows,
                           const int* __restrict__ cols, int nnz,
                           float* __restrict__ off_all,
                           float* __restrict__ diag_all) {
    int m = blockIdx.x;
    int i = threadIdx.x;                       // row, 0..15
    const float* e = (m == 0) ? e_in : (m <= 8) ? e_res + (size_t)(m - 1) * nnz : e_out;
    float l[16];
    for (int j = 0; j < 16; j++) l[j] = NEGV;
    for (int k = 0; k < nnz; k++)
        if (rows[k] == i) l[cols[k]] = e[k];
    float mx = l[0];
    for (int j = 1; j < 16; j++) mx = fmaxf(mx, l[j]);
    float ex[16], s = 0.f;
    for (int j = 0; j < 16; j++) { ex[j] = expf(l[j] - mx); s += ex[j]; }
    float inv = 1.f / s;
    for (int j = 0; j < 16; j++) {
        float a = ex[j] * inv;
        if (j == i) { diag_all[m * 16 + i] = a; a = 0.f; }
        off_all[m * 256 + i * 16 + j] = a;
    }
}

// ---------------------------------------------------------------- gconv (in, F=2)
__global__ void gconv_in_kernel(const float* __restrict__ x,
                                const float* __restrict__ W,   // (2,2,128)
                                const float* __restrict__ bias,
                                const float* __restrict__ off,
                                const float* __restrict__ diag,
                                float* __restrict__ out) {
    __shared__ float xs[16][2];
    __shared__ float gs[16][2];
    int b = blockIdx.x, t = threadIdx.x;
    if (t < 32) xs[t >> 1][t & 1] = x[b * 32 + t];
    __syncthreads();
    if (t < 32) {
        int i = t >> 1, f = t & 1;
        float g = 0.f;
        #pragma unroll
        for (int j = 0; j < 16; j++) g += off[i * 16 + j] * xs[j][f];
        gs[i][f] = g;
    }
    __syncthreads();
    for (int idx = t; idx < 2048; idx += 256) {
        int i = idx >> 7, o = idx & 127;
        float v = diag[i] * (xs[i][0] * W[o] + xs[i][1] * W[128 + o])
                + gs[i][0] * W[256 + o] + gs[i][1] * W[384 + o] + bias[o];
        out[b * 2048 + idx] = v;
    }
}

// ---------------------------------------------------------------- gconv 128->128
__global__ __launch_bounds__(256) void gconv128_kernel(
        const float* __restrict__ h,
        const float* __restrict__ W,      // (2,128,128)
        const float* __restrict__ bias,   // (128)
        const float* __restrict__ off,    // (16,16)
        const float* __restrict__ diag,   // (16)
        float* __restrict__ out) {
    __shared__ float hs[16][128];
    __shared__ float gs[16][128];
    int b = blockIdx.x, t = threadIdx.x;
    for (int idx = t; idx < 2048; idx += 256)
        ((float*)hs)[idx] = h[(size_t)b * 2048 + idx];
    __syncthreads();
    for (int idx = t; idx < 2048; idx += 256) {
        int i = idx >> 7, f = idx & 127;
        float g = 0.f;
        #pragma unroll
        for (int j = 0; j < 16; j++) g += off[i * 16 + j] * hs[j][f];
        gs[i][f] = g;
    }
    __syncthreads();
    int o = t & 127;
    int ibase = (t >> 7) * 8;                 // 0 or 8
    float acc0[8] = {0,0,0,0,0,0,0,0};
    float acc1[8] = {0,0,0,0,0,0,0,0};
    const float* W0 = W + o;
    const float* W1 = W + 16384 + o;
    for (int f = 0; f < 128; f++) {
        float w0 = W0[f * 128];
        float w1 = W1[f * 128];
        #pragma unroll
        for (int i = 0; i < 8; i++) {
            acc0[i] += hs[ibase + i][f] * w0;
            acc1[i] += gs[ibase + i][f] * w1;
        }
    }
    float bo = bias[o];
    #pragma unroll
    for (int i = 0; i < 8; i++) {
        float d = diag[ibase + i];
        out[(size_t)b * 2048 + (ibase + i) * 128 + o] = d * acc0[i] + acc1[i] + bo;
    }
}

// ---------------------------------------------------------------- per-channel stats
// t: (65536,128), stats: sum[128] then sumsq[128]  (must be pre-zeroed)
__global__ void stats_kernel(const float* __restrict__ t, float* __restrict__ stats) {
    __shared__ float ssum[256], ssq[256];
    int tid = threadIdx.x;
    int c = tid & 127;
    int r = blockIdx.x * 512 + (tid >> 7);
    float s = 0.f, q = 0.f;
    for (int k = 0; k < 256; k++) {
        float v = t[(size_t)(r + k * 2) * 128 + c];
        s += v; q += v * v;
    }
    ssum[tid] = s; ssq[tid] = q;
    __syncthreads();
    if (tid < 128) {
        s = ssum[tid] + ssum[tid + 128];
        q = ssq[tid] + ssq[tid + 128];
        atomicAdd(&stats[c], s);
        atomicAdd(&stats[128 + c], q);
    }
}

// ---------------------------------------------------------------- bn + relu (+res)
__global__ void bn_relu_kernel(const float* __restrict__ t,
                               const float* __restrict__ stats,
                               const float* __restrict__ g,
                               const float* __restrict__ bta,
                               const float* __restrict__ res,
                               float* __restrict__ out) {
    size_t idx = (size_t)blockIdx.x * 256 + threadIdx.x;
    int c = (int)(idx & 127);
    float mean = stats[c] * (1.f / 65536.f);
    float var = stats[128 + c] * (1.f / 65536.f) - mean * mean;
    float v = (t[idx] - mean) * rsqrtf(var + 1e-5f) * g[c] + bta[c];
    v = fmaxf(v, 0.f);
    if (res) v += res[idx];
    out[idx] = v;
}

// ---------------------------------------------------------------- nonlocal part A
// per-sample: xc -> conv g/t/p -> pool -> tv/pv -> f -> y -> Wy  (pre-bn)
// writes Wy transposed: wy_out[b, jg, o] = Wy[b, o, jg]
__global__ __launch_bounds__(256) void nl_a_kernel(
        const float* __restrict__ h,
        const float* __restrict__ g_w, const float* __restrict__ g_b,
        const float* __restrict__ t_w, const float* __restrict__ t_b,
        const float* __restrict__ p_w, const float* __restrict__ p_b,
        const float* __restrict__ cp_w,
        const float* __restrict__ W_w, const float* __restrict__ W_b,
        const int* __restrict__ restored,
        float* __restrict__ wy_out) {
    __shared__ float xc[128][17];
    __shared__ float th[64][16];
    __shared__ float gx[64][8];
    __shared__ float ph[64][8];
    __shared__ float ys[64][16];
    __shared__ float tv[16];
    __shared__ float pv[8];
    __shared__ int ro[16];
    int b = blockIdx.x, t = threadIdx.x;
    if (t < 16) ro[t] = restored[t];
    __syncthreads();
    for (int idx = t; idx < 2048; idx += 256) {
        int j = idx >> 7, c = idx & 127;
        xc[c][ro[j]] = h[(size_t)b * 2048 + idx];
    }
    __syncthreads();
    if (t < 192) {
        int conv = t >> 6, o = t & 63;
        const float* w = (conv == 0 ? g_w : conv == 1 ? t_w : p_w) + o * 128;
        float bb = (conv == 0 ? g_b : conv == 1 ? t_b : p_b)[o];
        float acc[16];
        #pragma unroll
        for (int j = 0; j < 16; j++) acc[j] = bb;
        for (int c = 0; c < 128; c++) {
            float wv = w[c];
            #pragma unroll
            for (int j = 0; j < 16; j++) acc[j] += wv * xc[c][j];
        }
        if (conv == 1) {
            #pragma unroll
            for (int j = 0; j < 16; j++) th[o][j] = acc[j];
        } else if (conv == 0) {
            #pragma unroll
            for (int w2 = 0; w2 < 8; w2++) gx[o][w2] = fmaxf(acc[2 * w2], acc[2 * w2 + 1]);
        } else {
            #pragma unroll
            for (int w2 = 0; w2 < 8; w2++) ph[o][w2] = fmaxf(acc[2 * w2], acc[2 * w2 + 1]);
        }
    }
    __syncthreads();
    if (t < 16) {
        float s = 0.f;
        for (int c = 0; c < 64; c++) s += th[c][t] * cp_w[c];
        tv[t] = s;
    } else if (t < 24) {
        int w2 = t - 16;
        float s = 0.f;
        for (int c = 0; c < 64; c++) s += ph[c][w2] * cp_w[64 + c];
        pv[w2] = s;
    }
    __syncthreads();
    for (int idx = t; idx < 1024; idx += 256) {
        int c = idx >> 4, j = idx & 15;
        float s = 0.f;
        #pragma unroll
        for (int w2 = 0; w2 < 8; w2++) {
            float f = fmaxf(tv[j] + pv[w2], 0.f) * 0.125f;
            s += f * gx[c][w2];
        }
        ys[c][j] = s;
    }
    __syncthreads();
    if (t < 128) {
        int o = t;
        float bo = W_b[o];
        float acc[16];
        #pragma unroll
        for (int j = 0; j < 16; j++) acc[j] = bo;
        for (int c = 0; c < 64; c++) {
            float wv = W_w[o * 64 + c];
            #pragma unroll
            for (int j = 0; j < 16; j++) acc[j] += wv * ys[c][j];
        }
        #pragma unroll
        for (int j = 0; j < 16; j++) xc[o][j] = acc[j];   // stage (reuse xc)
    }
    __syncthreads();
    for (int idx = t; idx < 2048; idx += 256) {
        int j = idx >> 7, o = idx & 127;
        wy_out[(size_t)b * 2048 + idx] = xc[o][j];
    }
}

// ---------------------------------------------------------------- nonlocal part B
// out[b,r,c] = bn(wy[b, restored[r], c]) + h[b,r,c]   (no relu)
__global__ void nl_b_kernel(const float* __restrict__ wy,
                            const float* __restrict__ stats,
                            const float* __restrict__ g,
                            const float* __restrict__ bta,
                            const float* __restrict__ h,
                            const int* __restrict__ restored,
                            float* __restrict__ out) {
    size_t idx = (size_t)blockIdx.x * 256 + threadIdx.x;
    int c = (int)(idx & 127);
    int r = (int)((idx >> 7) & 15);
    size_t b = idx >> 11;
    int jg = restored[r];
    float mean = stats[c] * (1.f / 65536.f);
    float var = stats[128 + c] * (1.f / 65536.f) - mean * mean;
    float v = (wy[(b * 16 + jg) * 128 + c] - mean) * rsqrtf(var + 1e-5f) * g[c] + bta[c];
    out[idx] = v + h[idx];
}

// ---------------------------------------------------------------- gconv out (128->3)
__global__ __launch_bounds__(64) void gconv_out_kernel(
        const float* __restrict__ h,
        const float* __restrict__ W,      // (2,128,3)
        const float* __restrict__ bias,   // (3)
        const float* __restrict__ off,
        const float* __restrict__ diag,
        float* __restrict__ out) {
    __shared__ float hs[16][128];
    __shared__ float gs[16][128];
    int b = blockIdx.x, t = threadIdx.x;
    for (int idx = t; idx < 2048; idx += 64)
        ((float*)hs)[idx] = h[(size_t)b * 2048 + idx];
    __syncthreads();
    for (int idx = t; idx < 2048; idx += 64) {
        int i = idx >> 7, f = idx & 127;
        float g = 0.f;
        #pragma unroll
        for (int j = 0; j < 16; j++) g += off[i * 16 + j] * hs[j][f];
        gs[i][f] = g;
    }
    __syncthreads();
    if (t < 48) {
        int i = t / 3, o = t % 3;
        float a0 = 0.f, a1 = 0.f;
        for (int f = 0; f < 128; f++) {
            a0 += hs[i][f] * W[f * 3 + o];
            a1 += gs[i][f] * W[384 + f * 3 + o];
        }
        out[b * 48 + t] = diag[i] * a0 + a1 + bias[o];
    }
}

// ================================================================ launch
extern "C" void kernel_launch(void* const* d_in, const int* in_sizes, int n_in,
                              void* d_out, int out_size, void* d_ws, size_t ws_size,
                              hipStream_t stream) {
    (void)n_in; (void)out_size; (void)ws_size;
    const float* x        = (const float*)d_in[0];
    const float* gc_in_W  = (const float*)d_in[1];
    const float* gc_in_e  = (const float*)d_in[2];
    const float* gc_in_b  = (const float*)d_in[3];
    const float* bn_in_g  = (const float*)d_in[4];
    const float* bn_in_b  = (const float*)d_in[5];
    const float* W_res    = (const float*)d_in[6];
    const float* e_res    = (const float*)d_in[7];
    const float* b_res    = (const float*)d_in[8];
    const float* bng_res  = (const float*)d_in[9];
    const float* bnb_res  = (const float*)d_in[10];
    const float* nl_g_w   = (const float*)d_in[11];
    const float* nl_g_b   = (const float*)d_in[12];
    const float* nl_t_w   = (const float*)d_in[13];
    const float* nl_t_b   = (const float*)d_in[14];
    const float* nl_p_w   = (const float*)d_in[15];
    const float* nl_p_b   = (const float*)d_in[16];
    const float* nl_cp_w  = (const float*)d_in[17];
    const float* nl_W_w   = (const float*)d_in[18];
    const float* nl_W_b   = (const float*)d_in[19];
    const float* nl_bn_g  = (const float*)d_in[20];
    const float* nl_bn_b  = (const float*)d_in[21];
    const float* gc_out_W = (const float*)d_in[22];
    const float* gc_out_e = (const float*)d_in[23];
    const float* gc_out_b = (const float*)d_in[24];
    const int*   mask_rows = (const int*)d_in[25];
    const int*   mask_cols = (const int*)d_in[26];
    const int*   restored  = (const int*)d_in[28];
    int nnz = in_sizes[2];

    float* ws       = (float*)d_ws;
    float* off_all  = ws;               // 10*256
    float* diag_all = ws + 2560;        // 10*16
    float* stats    = ws + 2720;        // 14*256
    float* buf0     = ws + 8192;        // (B,16,128)
    float* buf1     = buf0 + ELEMS;     // (B,16,128)

    hipMemsetAsync(stats, 0, 14 * 256 * sizeof(float), stream);
    adj_kernel<<<10, 16, 0, stream>>>(gc_in_e, e_res, gc_out_e, mask_rows, mask_cols,
                                      nnz, off_all, diag_all);

    int k = 0;
    // input graph_conv: x -> buf1 (pre-bn) -> buf0
    gconv_in_kernel<<<B, 256, 0, stream>>>(x, gc_in_W, gc_in_b, off_all, diag_all, buf1);
    stats_kernel<<<128, 256, 0, stream>>>(buf1, stats + k * 256);
    bn_relu_kernel<<<32768, 256, 0, stream>>>(buf1, stats + k * 256, bn_in_g, bn_in_b,
                                              nullptr, buf0);
    k++;
    // nonlocal 0 (in-place on buf0)
    nl_a_kernel<<<B, 256, 0, stream>>>(buf0, nl_g_w, nl_g_b, nl_t_w, nl_t_b,
                                       nl_p_w, nl_p_b, nl_cp_w, nl_W_w, nl_W_b,
                                       restored, buf1);
    stats_kernel<<<128, 256, 0, stream>>>(buf1, stats + k * 256);
    nl_b_kernel<<<32768, 256, 0, stream>>>(buf1, stats + k * 256, nl_bn_g, nl_bn_b,
                                           buf0, restored, buf0);
    k++;

    for (int i = 0; i < NLAYERS; i++) {
        int l0 = 2 * i, l1 = 2 * i + 1;
        // graph_conv 1: buf0 -> buf1 -> buf1 (in-place bn)
        gconv128_kernel<<<B, 256, 0, stream>>>(buf0, W_res + (size_t)l0 * 32768,
                                               b_res + l0 * 128,
                                               off_all + (1 + l0) * 256,
                                               diag_all + (1 + l0) * 16, buf1);
        stats_kernel<<<128, 256, 0, stream>>>(buf1, stats + k * 256);
        bn_relu_kernel<<<32768, 256, 0, stream>>>(buf1, stats + k * 256,
                                                  bng_res + l0 * 128, bnb_res + l0 * 128,
                                                  nullptr, buf1);
        k++;
        // graph_conv 2: buf1 -> buf1 (in-place: per-block LDS staging), +res -> buf0
        gconv128_kernel<<<B, 256, 0, stream>>>(buf1, W_res + (size_t)l1 * 32768,
                                               b_res + l1 * 128,
                                               off_all + (1 + l1) * 256,
                                               diag_all + (1 + l1) * 16, buf1);
        stats_kernel<<<128, 256, 0, stream>>>(buf1, stats + k * 256);
        bn_relu_kernel<<<32768, 256, 0, stream>>>(buf1, stats + k * 256,
                                                  bng_res + l1 * 128, bnb_res + l1 * 128,
                                                  buf0, buf0);
        k++;
        // nonlocal i+1 (in-place on buf0)
        int li = i + 1;
        nl_a_kernel<<<B, 256, 0, stream>>>(buf0, nl_g_w + li * 8192, nl_g_b + li * 64,
                                           nl_t_w + li * 8192, nl_t_b + li * 64,
                                           nl_p_w + li * 8192, nl_p_b + li * 64,
                                           nl_cp_w + li * 128, nl_W_w + li * 8192,
                                           nl_W_b + li * 128, restored, buf1);
        stats_kernel<<<128, 256, 0, stream>>>(buf1, stats + k * 256);
        nl_b_kernel<<<32768, 256, 0, stream>>>(buf1, stats + k * 256,
                                               nl_bn_g + li * 128, nl_bn_b + li * 128,
                                               buf0, restored, buf0);
        k++;
    }
    gconv_out_kernel<<<B, 64, 0, stream>>>(buf0, gc_out_W, gc_out_b,
                                           off_all + 9 * 256, diag_all + 9 * 16,
                                           (float*)d_out);
}

// Round 3
// 1974.797 us; speedup vs baseline: 1.1614x; 1.1614x over previous
//
#include <hip/hip_runtime.h>

#define B 4096
#define J 16
#define HID 128
#define INTER 64
#define NLAYERS 4
#define NEGV -9000000000000000.0f
#define ELEMS ((size_t)B*16*128)

typedef __attribute__((ext_vector_type(8))) short short8;
typedef __attribute__((ext_vector_type(4))) float f32x4;

static __device__ __forceinline__ unsigned short f2bf(float x) {
    unsigned u = __float_as_uint(x);
    unsigned r = u + 0x7fffu + ((u >> 16) & 1u);
    return (unsigned short)(r >> 16);
}
// split x = hi + lo, both bf16; |err| ~ 2^-18 |x|
static __device__ __forceinline__ void splitbf(float x, unsigned short& h, unsigned short& l) {
    h = f2bf(x);
    float hf = __uint_as_float((unsigned)h << 16);
    l = f2bf(x - hf);
}
static __device__ __forceinline__ f32x4 mfma16(short8 a, short8 b, f32x4 c) {
    return __builtin_amdgcn_mfma_f32_16x16x32_bf16(a, b, c, 0, 0, 0);
}
// 3-term split product accumulate: acc += A*B with A=(ah,al), B=(bh,bl)
static __device__ __forceinline__ f32x4 mfma_split(short8 ah, short8 al,
                                                   short8 bh, short8 bl, f32x4 acc) {
    acc = mfma16(ah, bh, acc);
    acc = mfma16(ah, bl, acc);
    acc = mfma16(al, bh, acc);
    return acc;
}

// ---------------------------------------------------------------- adjacency
__global__ void adj_kernel(const float* __restrict__ e_in,
                           const float* __restrict__ e_res,
                           const float* __restrict__ e_out,
                           const int* __restrict__ rows,
                           const int* __restrict__ cols, int nnz,
                           float* __restrict__ off_all,
                           float* __restrict__ diag_all) {
    int m = blockIdx.x;
    int i = threadIdx.x;
    const float* e = (m == 0) ? e_in : (m <= 8) ? e_res + (size_t)(m - 1) * nnz : e_out;
    float l[16];
    for (int j = 0; j < 16; j++) l[j] = NEGV;
    for (int k = 0; k < nnz; k++)
        if (rows[k] == i) l[cols[k]] = e[k];
    float mx = l[0];
    for (int j = 1; j < 16; j++) mx = fmaxf(mx, l[j]);
    float ex[16], s = 0.f;
    for (int j = 0; j < 16; j++) { ex[j] = expf(l[j] - mx); s += ex[j]; }
    float inv = 1.f / s;
    for (int j = 0; j < 16; j++) {
        float a = ex[j] * inv;
        if (j == i) { diag_all[m * 16 + i] = a; a = 0.f; }
        off_all[m * 256 + i * 16 + j] = a;
    }
}

// ---------------------------------------------------------------- weight prep (fp32 -> split bf16 hi/lo)
#define WB_N   262144     // 8 * 128 * 256  (Wb[l][n][k], k<128 -> W0, k>=128 -> W1)
#define NLW_N  122880     // 5 * 3 * 64 * 128
#define NLWW_N 40960      // 5 * 128 * 64
__global__ void prep_w_kernel(const float* __restrict__ W_res,
                              const float* __restrict__ g_w, const float* __restrict__ t_w,
                              const float* __restrict__ p_w, const float* __restrict__ W_w,
                              unsigned short* __restrict__ Wbh, unsigned short* __restrict__ Wbl,
                              unsigned short* __restrict__ nlwh, unsigned short* __restrict__ nlwl,
                              unsigned short* __restrict__ nlWh, unsigned short* __restrict__ nlWl) {
    int i = blockIdx.x * 256 + threadIdx.x;
    unsigned short h, l;
    if (i < WB_N) {
        int lay = i >> 15, rem = i & 32767, n = rem >> 8, k = rem & 255;
        int d = k >> 7, f = k & 127;
        splitbf(W_res[(((lay << 1) | d) * 128 + f) * 128 + n], h, l);
        Wbh[i] = h; Wbl[i] = l;
    } else if (i < WB_N + NLW_N) {
        int j = i - WB_N;
        int lay = j / 24576, r2 = j % 24576;
        int conv = r2 >> 13, oc = r2 & 8191;
        const float* src = conv == 0 ? g_w : conv == 1 ? t_w : p_w;
        splitbf(src[lay * 8192 + oc], h, l);
        nlwh[j] = h; nlwl[j] = l;
    } else if (i < WB_N + NLW_N + NLWW_N) {
        int j = i - WB_N - NLW_N;
        splitbf(W_w[j], h, l);
        nlWh[j] = h; nlWl[j] = l;
    }
}

// ---------------------------------------------------------------- gconv in (F=2), fused stats (fp32)
__global__ __launch_bounds__(256) void gconv_in_kernel(
        const float* __restrict__ x, const float* __restrict__ W,
        const float* __restrict__ bias, const float* __restrict__ off,
        const float* __restrict__ diag, float* __restrict__ out,
        float* __restrict__ stats_out) {
    __shared__ float xs[16][2];
    __shared__ float gs[16][2];
    __shared__ float red[512];
    int b = blockIdx.x, t = threadIdx.x;
    if (t < 32) xs[t >> 1][t & 1] = x[b * 32 + t];
    __syncthreads();
    if (t < 32) {
        int i = t >> 1, f = t & 1;
        float g = 0.f;
        #pragma unroll
        for (int j = 0; j < 16; j++) g += off[i * 16 + j] * xs[j][f];
        gs[i][f] = g;
    }
    __syncthreads();
    int o = t & 127;
    float w00 = W[o], w01 = W[128 + o], w10 = W[256 + o], w11 = W[384 + o], bo = bias[o];
    float s = 0.f, q = 0.f;
    for (int idx = t; idx < 2048; idx += 256) {
        int i = idx >> 7;
        float v = diag[i] * (xs[i][0] * w00 + xs[i][1] * w01)
                + gs[i][0] * w10 + gs[i][1] * w11 + bo;
        out[(size_t)b * 2048 + idx] = v;
        s += v; q += v * v;
    }
    red[t] = s; red[256 + t] = q;
    __syncthreads();
    if (t < 128) {
        atomicAdd(&stats_out[t], red[t] + red[t + 128]);
        atomicAdd(&stats_out[128 + t], red[256 + t] + red[256 + t + 128]);
    }
}

// ---------------------------------------------------------------- gconv 128->128 via split-bf16 MFMA
__global__ __launch_bounds__(256) void gconv_mfma_kernel(
        const float* src, const float* __restrict__ stats_in,
        const float* __restrict__ bn_g, const float* __restrict__ bn_b,
        const unsigned short* __restrict__ Wbh,   // [128][256] bf16 hi
        const unsigned short* __restrict__ Wbl,   // [128][256] bf16 lo
        const float* __restrict__ bias,
        const float* __restrict__ off, const float* __restrict__ diag,
        float* dst, float* __restrict__ stats_out) {
    __shared__ float hraw[16][132];
    __shared__ __align__(16) unsigned short ksh[16][264];
    __shared__ __align__(16) unsigned short ksl[16][264];
    __shared__ float offs[256];
    __shared__ float diags[16];
    int b = blockIdx.x, t = threadIdx.x;
    offs[t] = off[t];
    if (t < 16) diags[t] = diag[t];
    {
        int c = t & 127;
        float mean = 0.f, inv = 0.f, bb = 0.f;
        if (stats_in) {
            mean = stats_in[c] * (1.f / 65536.f);
            float var = stats_in[128 + c] * (1.f / 65536.f) - mean * mean;
            inv = rsqrtf(var + 1e-5f) * bn_g[c];
            bb = bn_b[c];
        }
        for (int idx = t; idx < 2048; idx += 256) {
            float v = src[(size_t)b * 2048 + idx];
            if (stats_in) v = fmaxf((v - mean) * inv + bb, 0.f);
            hraw[idx >> 7][idx & 127] = v;
        }
    }
    __syncthreads();
    // mix (off@h) + diag-fold + split-bf16 convert; units (i, f4)
    for (int u = t; u < 512; u += 256) {
        int i = u >> 5, f4 = (u & 31) << 2;
        float4 hv = *(const float4*)&hraw[i][f4];
        float4 g = make_float4(0.f, 0.f, 0.f, 0.f);
        #pragma unroll
        for (int j = 0; j < 16; j++) {
            float w = offs[i * 16 + j];
            float4 hj = *(const float4*)&hraw[j][f4];
            g.x += w * hj.x; g.y += w * hj.y; g.z += w * hj.z; g.w += w * hj.w;
        }
        float d = diags[i];
        unsigned short h0,l0,h1,l1,h2,l2,h3,l3;
        splitbf(d * hv.x, h0, l0); splitbf(d * hv.y, h1, l1);
        splitbf(d * hv.z, h2, l2); splitbf(d * hv.w, h3, l3);
        *(uint2*)&ksh[i][f4] = make_uint2((unsigned)h0 | ((unsigned)h1 << 16),
                                          (unsigned)h2 | ((unsigned)h3 << 16));
        *(uint2*)&ksl[i][f4] = make_uint2((unsigned)l0 | ((unsigned)l1 << 16),
                                          (unsigned)l2 | ((unsigned)l3 << 16));
        splitbf(g.x, h0, l0); splitbf(g.y, h1, l1);
        splitbf(g.z, h2, l2); splitbf(g.w, h3, l3);
        *(uint2*)&ksh[i][128 + f4] = make_uint2((unsigned)h0 | ((unsigned)h1 << 16),
                                                (unsigned)h2 | ((unsigned)h3 << 16));
        *(uint2*)&ksl[i][128 + f4] = make_uint2((unsigned)l0 | ((unsigned)l1 << 16),
                                                (unsigned)l2 | ((unsigned)l3 << 16));
    }
    __syncthreads();
    int wv = t >> 6, lane = t & 63;
    int mn = lane & 15, kq = (lane >> 4) << 3, qr = (lane >> 4) << 2;
    int n0 = wv << 5;
    f32x4 acc0 = {0.f, 0.f, 0.f, 0.f}, acc1 = {0.f, 0.f, 0.f, 0.f};
    const unsigned short* wh0 = Wbh + (size_t)(n0 + mn) * 256 + kq;
    const unsigned short* wl0 = Wbl + (size_t)(n0 + mn) * 256 + kq;
    #pragma unroll
    for (int s = 0; s < 8; s++) {
        int k0 = s << 5;
        short8 ah = *(const short8*)&ksh[mn][k0 + kq];
        short8 al = *(const short8*)&ksl[mn][k0 + kq];
        acc0 = mfma_split(ah, al, *(const short8*)(wh0 + k0), *(const short8*)(wl0 + k0), acc0);
        acc1 = mfma_split(ah, al, *(const short8*)(wh0 + 4096 + k0), *(const short8*)(wl0 + 4096 + k0), acc1);
    }
    float bias0 = bias[n0 + mn], bias1 = bias[n0 + 16 + mn];
    float s0 = 0.f, q0 = 0.f, s1 = 0.f, q1 = 0.f;
    #pragma unroll
    for (int r = 0; r < 4; r++) {
        int row = qr + r;
        float v0 = acc0[r] + bias0;
        float v1 = acc1[r] + bias1;
        dst[(size_t)b * 2048 + row * 128 + n0 + mn] = v0;
        dst[(size_t)b * 2048 + row * 128 + n0 + 16 + mn] = v1;
        s0 += v0; q0 += v0 * v0; s1 += v1; q1 += v1 * v1;
    }
    s0 += __shfl_xor(s0, 16); s0 += __shfl_xor(s0, 32);
    q0 += __shfl_xor(q0, 16); q0 += __shfl_xor(q0, 32);
    s1 += __shfl_xor(s1, 16); s1 += __shfl_xor(s1, 32);
    q1 += __shfl_xor(q1, 16); q1 += __shfl_xor(q1, 32);
    if (lane < 16) {
        atomicAdd(&stats_out[n0 + mn], s0);
        atomicAdd(&stats_out[128 + n0 + mn], q0);
        atomicAdd(&stats_out[n0 + 16 + mn], s1);
        atomicAdd(&stats_out[128 + n0 + 16 + mn], q1);
    }
}

// ---------------------------------------------------------------- nonlocal A (split-bf16 MFMA convs)
__global__ __launch_bounds__(256) void nl_a_kernel(
        const float* tsrc, const float* __restrict__ stats_in,
        const float* __restrict__ bn_g, const float* __restrict__ bn_b,
        const float* res,
        const unsigned short* __restrict__ nlwh,  // [3][64][128] hi
        const unsigned short* __restrict__ nlwl,  // lo
        const float* __restrict__ g_b, const float* __restrict__ t_b,
        const float* __restrict__ p_b, const float* __restrict__ cpw,
        const unsigned short* __restrict__ nlWh,  // [128][64] hi
        const unsigned short* __restrict__ nlWl,  // lo
        const float* __restrict__ W_b,
        const int* __restrict__ restored,
        float* hdst, float* wydst, float* __restrict__ wst) {
    __shared__ __align__(16) unsigned short xch[16][136];
    __shared__ __align__(16) unsigned short xcl[16][136];
    __shared__ float cg[3][64][17];
    __shared__ float gx[64][9];
    __shared__ float tv[16], pv[8];
    __shared__ __align__(16) unsigned short ybh[16][72];
    __shared__ __align__(16) unsigned short ybl[16][72];
    __shared__ float wyl[128][17];
    __shared__ int ro[16];
    int b = blockIdx.x, t = threadIdx.x;
    if (t < 16) ro[t] = restored[t];
    __syncthreads();
    {
        int c = t & 127;
        float mean = 0.f, inv = 0.f, bb = 0.f;
        if (stats_in) {
            mean = stats_in[c] * (1.f / 65536.f);
            float var = stats_in[128 + c] * (1.f / 65536.f) - mean * mean;
            inv = rsqrtf(var + 1e-5f) * bn_g[c];
            bb = bn_b[c];
        }
        for (int idx = t; idx < 2048; idx += 256) {
            int r = idx >> 7;
            float v = tsrc[(size_t)b * 2048 + idx];
            if (stats_in) v = fmaxf((v - mean) * inv + bb, 0.f);
            if (res) v += res[(size_t)b * 2048 + idx];
            hdst[(size_t)b * 2048 + idx] = v;
            unsigned short h, l;
            splitbf(v, h, l);
            xch[ro[r]][c] = h;
            xcl[ro[r]][c] = l;
        }
    }
    __syncthreads();
    int wv = t >> 6, lane = t & 63;
    int mn = lane & 15, kq = (lane >> 4) << 3, qr = (lane >> 4) << 2;
    {
        short8 bh[4], bl[4];
        #pragma unroll
        for (int s = 0; s < 4; s++) {
            bh[s] = *(const short8*)&xch[mn][s * 32 + kq];
            bl[s] = *(const short8*)&xcl[mn][s * 32 + kq];
        }
        #pragma unroll
        for (int jj = 0; jj < 3; jj++) {
            int jb = wv + jj * 4;
            int conv = jb >> 2, mt = jb & 3;
            const unsigned short* aph = nlwh + (conv * 64 + mt * 16 + mn) * 128 + kq;
            const unsigned short* apl = nlwl + (conv * 64 + mt * 16 + mn) * 128 + kq;
            f32x4 acc = {0.f, 0.f, 0.f, 0.f};
            #pragma unroll
            for (int s = 0; s < 4; s++)
                acc = mfma_split(*(const short8*)(aph + s * 32), *(const short8*)(apl + s * 32),
                                 bh[s], bl[s], acc);
            const float* bias = conv == 0 ? g_b : conv == 1 ? t_b : p_b;
            #pragma unroll
            for (int r = 0; r < 4; r++) {
                int o = mt * 16 + qr + r;
                cg[conv][o][mn] = acc[r] + bias[o];
            }
        }
    }
    __syncthreads();
    for (int u = t; u < 512; u += 256) {
        int c = u >> 3, w2 = u & 7;
        gx[c][w2] = fmaxf(cg[0][c][2 * w2], cg[0][c][2 * w2 + 1]);
    }
    if (t < 16) {
        float s = 0.f;
        for (int c2 = 0; c2 < 64; c2++) s += cg[1][c2][t] * cpw[c2];
        tv[t] = s;
    }
    if (t >= 64 && t < 72) {
        int w2 = t - 64;
        float s = 0.f;
        for (int c2 = 0; c2 < 64; c2++)
            s += fmaxf(cg[2][c2][2 * w2], cg[2][c2][2 * w2 + 1]) * cpw[64 + c2];
        pv[w2] = s;
    }
    __syncthreads();
    for (int u = t; u < 1024; u += 256) {
        int j = u >> 6, c = u & 63;
        float s = 0.f;
        #pragma unroll
        for (int w2 = 0; w2 < 8; w2++)
            s += fmaxf(tv[j] + pv[w2], 0.f) * gx[c][w2];
        unsigned short h, l;
        splitbf(s * 0.125f, h, l);
        ybh[j][c] = h; ybl[j][c] = l;
    }
    __syncthreads();
    {
        short8 byh0 = *(const short8*)&ybh[mn][kq];
        short8 byh1 = *(const short8*)&ybh[mn][32 + kq];
        short8 byl0 = *(const short8*)&ybl[mn][kq];
        short8 byl1 = *(const short8*)&ybl[mn][32 + kq];
        #pragma unroll
        for (int mm = 0; mm < 2; mm++) {
            int mt = wv * 2 + mm;
            const unsigned short* aph = nlWh + (mt * 16 + mn) * 64 + kq;
            const unsigned short* apl = nlWl + (mt * 16 + mn) * 64 + kq;
            f32x4 acc = {0.f, 0.f, 0.f, 0.f};
            acc = mfma_split(*(const short8*)aph, *(const short8*)apl, byh0, byl0, acc);
            acc = mfma_split(*(const short8*)(aph + 32), *(const short8*)(apl + 32), byh1, byl1, acc);
            #pragma unroll
            for (int r = 0; r < 4; r++) {
                int o = mt * 16 + qr + r;
                wyl[o][mn] = acc[r] + W_b[o];
            }
        }
    }
    __syncthreads();
    {
        int c = t & 127;
        float s = 0.f, q = 0.f;
        for (int idx = t; idx < 2048; idx += 256) {
            int j = idx >> 7;
            float v = wyl[c][j];
            wydst[(size_t)b * 2048 + idx] = v;
            s += v; q += v * v;
        }
        float* red = (float*)cg;
        red[t] = s; red[256 + t] = q;
        __syncthreads();
        if (t < 128) {
            atomicAdd(&wst[t], red[t] + red[t + 128]);
            atomicAdd(&wst[128 + t], red[256 + t] + red[256 + t + 128]);
        }
    }
}

// ---------------------------------------------------------------- nonlocal B (fp32)
__global__ void nl_b_kernel(const float* __restrict__ wy, const float* __restrict__ wst,
                            const float* __restrict__ g, const float* __restrict__ bta,
                            const int* __restrict__ restored, float* z) {
    size_t i4 = (size_t)blockIdx.x * 256 + threadIdx.x;
    size_t idx = i4 << 2;
    int c = (int)(idx & 127);
    int r = (int)((idx >> 7) & 15);
    size_t b = idx >> 11;
    int jg = restored[r];
    float4 w = *(const float4*)&wy[((b << 4) + jg) * 128 + c];
    float4 zo = *(const float4*)&z[idx];
    float4 sm = *(const float4*)&wst[c];
    float4 sq = *(const float4*)&wst[128 + c];
    float4 gg = *(const float4*)&g[c];
    float4 bb = *(const float4*)&bta[c];
    float4 out;
    { float m = sm.x*(1.f/65536.f); float v = sq.x*(1.f/65536.f)-m*m;
      out.x = (w.x-m)*rsqrtf(v+1e-5f)*gg.x + bb.x + zo.x; }
    { float m = sm.y*(1.f/65536.f); float v = sq.y*(1.f/65536.f)-m*m;
      out.y = (w.y-m)*rsqrtf(v+1e-5f)*gg.y + bb.y + zo.y; }
    { float m = sm.z*(1.f/65536.f); float v = sq.z*(1.f/65536.f)-m*m;
      out.z = (w.z-m)*rsqrtf(v+1e-5f)*gg.z + bb.z + zo.z; }
    { float m = sm.w*(1.f/65536.f); float v = sq.w*(1.f/65536.f)-m*m;
      out.w = (w.w-m)*rsqrtf(v+1e-5f)*gg.w + bb.w + zo.w; }
    *(float4*)&z[idx] = out;
}

// ---------------------------------------------------------------- gconv out (128->3, fp32)
__global__ __launch_bounds__(256) void gconv_out_kernel(
        const float* __restrict__ h, const float* __restrict__ W,
        const float* __restrict__ bias, const float* __restrict__ off,
        const float* __restrict__ diag, float* __restrict__ out) {
    __shared__ float hs[16][128];
    __shared__ float gsv[16][128];
    __shared__ float offs[256];
    __shared__ float p0[48][4], p1[48][4];
    int b = blockIdx.x, t = threadIdx.x;
    offs[t] = off[t];
    for (int idx = t; idx < 2048; idx += 256)
        ((float*)hs)[idx] = h[(size_t)b * 2048 + idx];
    __syncthreads();
    for (int idx = t; idx < 2048; idx += 256) {
        int i = idx >> 7, f = idx & 127;
        float g = 0.f;
        #pragma unroll
        for (int j = 0; j < 16; j++) g += offs[i * 16 + j] * hs[j][f];
        gsv[i][f] = g;
    }
    __syncthreads();
    if (t < 192) {
        int oid = t >> 2, chunk = t & 3;
        int i = oid / 3, o = oid % 3;
        float a0 = 0.f, a1 = 0.f;
        int f0 = chunk * 32;
        for (int f = f0; f < f0 + 32; f++) {
            a0 += hs[i][f] * W[f * 3 + o];
            a1 += gsv[i][f] * W[384 + f * 3 + o];
        }
        p0[oid][chunk] = a0; p1[oid][chunk] = a1;
    }
    __syncthreads();
    if (t < 48) {
        int i = t / 3, o = t % 3;
        float a0 = p0[t][0] + p0[t][1] + p0[t][2] + p0[t][3];
        float a1 = p1[t][0] + p1[t][1] + p1[t][2] + p1[t][3];
        out[(size_t)b * 48 + t] = diag[i] * a0 + a1 + bias[o];
    }
}

// ================================================================ launch
extern "C" void kernel_launch(void* const* d_in, const int* in_sizes, int n_in,
                              void* d_out, int out_size, void* d_ws, size_t ws_size,
                              hipStream_t stream) {
    (void)n_in; (void)out_size; (void)ws_size;
    const float* x        = (const float*)d_in[0];
    const float* gc_in_W  = (const float*)d_in[1];
    const float* gc_in_e  = (const float*)d_in[2];
    const float* gc_in_b  = (const float*)d_in[3];
    const float* bn_in_g  = (const float*)d_in[4];
    const float* bn_in_b  = (const float*)d_in[5];
    const float* W_res    = (const float*)d_in[6];
    const float* e_res    = (const float*)d_in[7];
    const float* b_res    = (const float*)d_in[8];
    const float* bng_res  = (const float*)d_in[9];
    const float* bnb_res  = (const float*)d_in[10];
    const float* nl_g_w   = (const float*)d_in[11];
    const float* nl_g_b   = (const float*)d_in[12];
    const float* nl_t_w   = (const float*)d_in[13];
    const float* nl_t_b   = (const float*)d_in[14];
    const float* nl_p_w   = (const float*)d_in[15];
    const float* nl_p_b   = (const float*)d_in[16];
    const float* nl_cp_w  = (const float*)d_in[17];
    const float* nl_W_w   = (const float*)d_in[18];
    const float* nl_W_b   = (const float*)d_in[19];
    const float* nl_bn_g  = (const float*)d_in[20];
    const float* nl_bn_b  = (const float*)d_in[21];
    const float* gc_out_W = (const float*)d_in[22];
    const float* gc_out_e = (const float*)d_in[23];
    const float* gc_out_b = (const float*)d_in[24];
    const int*   mask_rows = (const int*)d_in[25];
    const int*   mask_cols = (const int*)d_in[26];
    const int*   restored  = (const int*)d_in[28];
    int nnz = in_sizes[2];

    float* ws        = (float*)d_ws;
    float* off_all   = ws;                 // 2560
    float* diag_all  = ws + 2560;          // 160
    float* stats     = ws + 2720;          // 14*256 = 3584 -> ends 6304
    unsigned short* Wbh  = (unsigned short*)(ws + 6400);
    unsigned short* Wbl  = Wbh + WB_N;
    unsigned short* nlwh = Wbl + WB_N;
    unsigned short* nlwl = nlwh + NLW_N;
    unsigned short* nlWh = nlwl + NLW_N;
    unsigned short* nlWl = nlWh + NLWW_N;  // ends at float 6400 + 425984 = 432384
    float* Z = ws + 432384;
    float* T = Z + ELEMS;                  // total 68.84 MB (R2 ran at 68.2 MB)

    hipMemsetAsync(stats, 0, 3584 * sizeof(float), stream);
    adj_kernel<<<10, 16, 0, stream>>>(gc_in_e, e_res, gc_out_e, mask_rows, mask_cols,
                                      nnz, off_all, diag_all);
    prep_w_kernel<<<(WB_N + NLW_N + NLWW_N + 255) / 256, 256, 0, stream>>>(
        W_res, nl_g_w, nl_t_w, nl_p_w, nl_W_w, Wbh, Wbl, nlwh, nlwl, nlWh, nlWl);

    gconv_in_kernel<<<B, 256, 0, stream>>>(x, gc_in_W, gc_in_b, off_all, diag_all,
                                           Z, stats);
    nl_a_kernel<<<B, 256, 0, stream>>>(Z, stats, bn_in_g, bn_in_b, nullptr,
                                       nlwh, nlwl, nl_g_b, nl_t_b, nl_p_b, nl_cp_w,
                                       nlWh, nlWl, nl_W_b, restored, Z, T, stats + 256);
    nl_b_kernel<<<8192, 256, 0, stream>>>(T, stats + 256, nl_bn_g, nl_bn_b, restored, Z);

    int sl = 2;
    for (int i = 0; i < NLAYERS; i++) {
        int l0 = 2 * i, l1 = 2 * i + 1, li = i + 1;
        gconv_mfma_kernel<<<B, 256, 0, stream>>>(
            Z, nullptr, nullptr, nullptr,
            Wbh + (size_t)l0 * 32768, Wbl + (size_t)l0 * 32768, b_res + l0 * 128,
            off_all + (1 + l0) * 256, diag_all + (1 + l0) * 16, T, stats + sl * 256);
        gconv_mfma_kernel<<<B, 256, 0, stream>>>(
            T, stats + sl * 256, bng_res + l0 * 128, bnb_res + l0 * 128,
            Wbh + (size_t)l1 * 32768, Wbl + (size_t)l1 * 32768, b_res + l1 * 128,
            off_all + (1 + l1) * 256, diag_all + (1 + l1) * 16, T, stats + (sl + 1) * 256);
        nl_a_kernel<<<B, 256, 0, stream>>>(
            T, stats + (sl + 1) * 256, bng_res + l1 * 128, bnb_res + l1 * 128, Z,
            nlwh + li * 24576, nlwl + li * 24576,
            nl_g_b + li * 64, nl_t_b + li * 64, nl_p_b + li * 64,
            nl_cp_w + li * 128, nlWh + li * 8192, nlWl + li * 8192, nl_W_b + li * 128,
            restored, Z, T, stats + (sl + 2) * 256);
        nl_b_kernel<<<8192, 256, 0, stream>>>(T, stats + (sl + 2) * 256,
                                              nl_bn_g + li * 128, nl_bn_b + li * 128,
                                              restored, Z);
        sl += 3;
    }
    gconv_out_kernel<<<B, 256, 0, stream>>>(Z, gc_out_W, gc_out_b,
                                            off_all + 9 * 256, diag_all + 9 * 16,
                                            (float*)d_out);
}

// Round 4
// 1289.722 us; speedup vs baseline: 1.7783x; 1.5312x over previous
//
#include <hip/hip_runtime.h>

#define B 4096
#define J 16
#define HID 128
#define INTER 64
#define NLAYERS 4
#define NEGV -9000000000000000.0f
#define ELEMS ((size_t)B*16*128)
#define NREP 16          // stats replicas (atomic spread); chain = 4096/16 = 256
#define SLOT 4096        // floats per stats slot = NREP*256

typedef __attribute__((ext_vector_type(8))) short short8;
typedef __attribute__((ext_vector_type(4))) float f32x4;

static __device__ __forceinline__ unsigned short f2bf(float x) {
    unsigned u = __float_as_uint(x);
    unsigned r = u + 0x7fffu + ((u >> 16) & 1u);
    return (unsigned short)(r >> 16);
}
// split x = hi + lo, both bf16; |err| ~ 2^-18 |x|
static __device__ __forceinline__ void splitbf(float x, unsigned short& h, unsigned short& l) {
    h = f2bf(x);
    float hf = __uint_as_float((unsigned)h << 16);
    l = f2bf(x - hf);
}
static __device__ __forceinline__ f32x4 mfma16(short8 a, short8 b, f32x4 c) {
    return __builtin_amdgcn_mfma_f32_16x16x32_bf16(a, b, c, 0, 0, 0);
}
static __device__ __forceinline__ f32x4 mfma_split(short8 ah, short8 al,
                                                   short8 bh, short8 bl, f32x4 acc) {
    acc = mfma16(ah, bh, acc);
    acc = mfma16(ah, bl, acc);
    acc = mfma16(al, bh, acc);
    return acc;
}
// sum NREP replicas of (sum, sumsq) for channel c; slot layout [rep][256]
static __device__ __forceinline__ void stats_sum(const float* __restrict__ slot, int c,
                                                 float& s, float& q) {
    s = 0.f; q = 0.f;
    #pragma unroll
    for (int r = 0; r < NREP; r++) {
        s += slot[r * 256 + c];
        q += slot[r * 256 + 128 + c];
    }
}

// ---------------------------------------------------------------- adjacency
__global__ void adj_kernel(const float* __restrict__ e_in,
                           const float* __restrict__ e_res,
                           const float* __restrict__ e_out,
                           const int* __restrict__ rows,
                           const int* __restrict__ cols, int nnz,
                           float* __restrict__ off_all,
                           float* __restrict__ diag_all) {
    int m = blockIdx.x;
    int i = threadIdx.x;
    const float* e = (m == 0) ? e_in : (m <= 8) ? e_res + (size_t)(m - 1) * nnz : e_out;
    float l[16];
    for (int j = 0; j < 16; j++) l[j] = NEGV;
    for (int k = 0; k < nnz; k++)
        if (rows[k] == i) l[cols[k]] = e[k];
    float mx = l[0];
    for (int j = 1; j < 16; j++) mx = fmaxf(mx, l[j]);
    float ex[16], s = 0.f;
    for (int j = 0; j < 16; j++) { ex[j] = expf(l[j] - mx); s += ex[j]; }
    float inv = 1.f / s;
    for (int j = 0; j < 16; j++) {
        float a = ex[j] * inv;
        if (j == i) { diag_all[m * 16 + i] = a; a = 0.f; }
        off_all[m * 256 + i * 16 + j] = a;
    }
}

// ---------------------------------------------------------------- weight prep (fp32 -> split bf16 hi/lo)
#define WB_N   262144     // 8 * 128 * 256  (Wb[l][n][k], k<128 -> W0, k>=128 -> W1)
#define NLW_N  122880     // 5 * 3 * 64 * 128
#define NLWW_N 40960      // 5 * 128 * 64
__global__ void prep_w_kernel(const float* __restrict__ W_res,
                              const float* __restrict__ g_w, const float* __restrict__ t_w,
                              const float* __restrict__ p_w, const float* __restrict__ W_w,
                              unsigned short* __restrict__ Wbh, unsigned short* __restrict__ Wbl,
                              unsigned short* __restrict__ nlwh, unsigned short* __restrict__ nlwl,
                              unsigned short* __restrict__ nlWh, unsigned short* __restrict__ nlWl) {
    int i = blockIdx.x * 256 + threadIdx.x;
    unsigned short h, l;
    if (i < WB_N) {
        int lay = i >> 15, rem = i & 32767, n = rem >> 8, k = rem & 255;
        int d = k >> 7, f = k & 127;
        splitbf(W_res[(((lay << 1) | d) * 128 + f) * 128 + n], h, l);
        Wbh[i] = h; Wbl[i] = l;
    } else if (i < WB_N + NLW_N) {
        int j = i - WB_N;
        int lay = j / 24576, r2 = j % 24576;
        int conv = r2 >> 13, oc = r2 & 8191;
        const float* src = conv == 0 ? g_w : conv == 1 ? t_w : p_w;
        splitbf(src[lay * 8192 + oc], h, l);
        nlwh[j] = h; nlwl[j] = l;
    } else if (i < WB_N + NLW_N + NLWW_N) {
        int j = i - WB_N - NLW_N;
        splitbf(W_w[j], h, l);
        nlWh[j] = h; nlWl[j] = l;
    }
}

// ---------------------------------------------------------------- stats finalize (for nl_b)
__global__ void finalize_kernel(const float* __restrict__ slot, float* __restrict__ fin) {
    int t = threadIdx.x;   // 256
    float s = 0.f;
    #pragma unroll
    for (int r = 0; r < NREP; r++) s += slot[r * 256 + t];
    fin[t] = s;
}

// ---------------------------------------------------------------- gconv in (F=2), fused stats
__global__ __launch_bounds__(256) void gconv_in_kernel(
        const float* __restrict__ x, const float* __restrict__ W,
        const float* __restrict__ bias, const float* __restrict__ off,
        const float* __restrict__ diag, float* __restrict__ out,
        float* __restrict__ stats_out) {
    __shared__ float xs[16][2];
    __shared__ float gs[16][2];
    __shared__ float red[512];
    int b = blockIdx.x, t = threadIdx.x;
    if (t < 32) xs[t >> 1][t & 1] = x[b * 32 + t];
    __syncthreads();
    if (t < 32) {
        int i = t >> 1, f = t & 1;
        float g = 0.f;
        #pragma unroll
        for (int j = 0; j < 16; j++) g += off[i * 16 + j] * xs[j][f];
        gs[i][f] = g;
    }
    __syncthreads();
    int o = t & 127;
    float w00 = W[o], w01 = W[128 + o], w10 = W[256 + o], w11 = W[384 + o], bo = bias[o];
    float s = 0.f, q = 0.f;
    for (int idx = t; idx < 2048; idx += 256) {
        int i = idx >> 7;
        float v = diag[i] * (xs[i][0] * w00 + xs[i][1] * w01)
                + gs[i][0] * w10 + gs[i][1] * w11 + bo;
        out[(size_t)b * 2048 + idx] = v;
        s += v; q += v * v;
    }
    red[t] = s; red[256 + t] = q;
    __syncthreads();
    float* so = stats_out + (b & (NREP - 1)) * 256;
    if (t < 128) {
        atomicAdd(&so[t], red[t] + red[t + 128]);
        atomicAdd(&so[128 + t], red[256 + t] + red[256 + t + 128]);
    }
}

// ---------------------------------------------------------------- gconv 128->128 via split-bf16 MFMA
__global__ __launch_bounds__(256) void gconv_mfma_kernel(
        const float* src, const float* __restrict__ stats_in,
        const float* __restrict__ bn_g, const float* __restrict__ bn_b,
        const unsigned short* __restrict__ Wbh,   // [128][256] bf16 hi
        const unsigned short* __restrict__ Wbl,   // [128][256] bf16 lo
        const float* __restrict__ bias,
        const float* __restrict__ off, const float* __restrict__ diag,
        float* dst, float* __restrict__ stats_out) {
    __shared__ float hraw[16][132];
    __shared__ __align__(16) unsigned short ksh[16][264];
    __shared__ __align__(16) unsigned short ksl[16][264];
    __shared__ float offs[256];
    __shared__ float diags[16];
    int b = blockIdx.x, t = threadIdx.x;
    offs[t] = off[t];
    if (t < 16) diags[t] = diag[t];
    {
        int c = t & 127;
        float mean = 0.f, inv = 0.f, bb = 0.f;
        if (stats_in) {
            float ssum, ssq;
            stats_sum(stats_in, c, ssum, ssq);
            mean = ssum * (1.f / 65536.f);
            float var = ssq * (1.f / 65536.f) - mean * mean;
            inv = rsqrtf(var + 1e-5f) * bn_g[c];
            bb = bn_b[c];
        }
        for (int idx = t; idx < 2048; idx += 256) {
            float v = src[(size_t)b * 2048 + idx];
            if (stats_in) v = fmaxf((v - mean) * inv + bb, 0.f);
            hraw[idx >> 7][idx & 127] = v;
        }
    }
    __syncthreads();
    for (int u = t; u < 512; u += 256) {
        int i = u >> 5, f4 = (u & 31) << 2;
        float4 hv = *(const float4*)&hraw[i][f4];
        float4 g = make_float4(0.f, 0.f, 0.f, 0.f);
        #pragma unroll
        for (int j = 0; j < 16; j++) {
            float w = offs[i * 16 + j];
            float4 hj = *(const float4*)&hraw[j][f4];
            g.x += w * hj.x; g.y += w * hj.y; g.z += w * hj.z; g.w += w * hj.w;
        }
        float d = diags[i];
        unsigned short h0,l0,h1,l1,h2,l2,h3,l3;
        splitbf(d * hv.x, h0, l0); splitbf(d * hv.y, h1, l1);
        splitbf(d * hv.z, h2, l2); splitbf(d * hv.w, h3, l3);
        *(uint2*)&ksh[i][f4] = make_uint2((unsigned)h0 | ((unsigned)h1 << 16),
                                          (unsigned)h2 | ((unsigned)h3 << 16));
        *(uint2*)&ksl[i][f4] = make_uint2((unsigned)l0 | ((unsigned)l1 << 16),
                                          (unsigned)l2 | ((unsigned)l3 << 16));
        splitbf(g.x, h0, l0); splitbf(g.y, h1, l1);
        splitbf(g.z, h2, l2); splitbf(g.w, h3, l3);
        *(uint2*)&ksh[i][128 + f4] = make_uint2((unsigned)h0 | ((unsigned)h1 << 16),
                                                (unsigned)h2 | ((unsigned)h3 << 16));
        *(uint2*)&ksl[i][128 + f4] = make_uint2((unsigned)l0 | ((unsigned)l1 << 16),
                                                (unsigned)l2 | ((unsigned)l3 << 16));
    }
    __syncthreads();
    int wv = t >> 6, lane = t & 63;
    int mn = lane & 15, kq = (lane >> 4) << 3, qr = (lane >> 4) << 2;
    int n0 = wv << 5;
    f32x4 acc0 = {0.f, 0.f, 0.f, 0.f}, acc1 = {0.f, 0.f, 0.f, 0.f};
    const unsigned short* wh0 = Wbh + (size_t)(n0 + mn) * 256 + kq;
    const unsigned short* wl0 = Wbl + (size_t)(n0 + mn) * 256 + kq;
    #pragma unroll
    for (int s = 0; s < 8; s++) {
        int k0 = s << 5;
        short8 ah = *(const short8*)&ksh[mn][k0 + kq];
        short8 al = *(const short8*)&ksl[mn][k0 + kq];
        acc0 = mfma_split(ah, al, *(const short8*)(wh0 + k0), *(const short8*)(wl0 + k0), acc0);
        acc1 = mfma_split(ah, al, *(const short8*)(wh0 + 4096 + k0), *(const short8*)(wl0 + 4096 + k0), acc1);
    }
    float bias0 = bias[n0 + mn], bias1 = bias[n0 + 16 + mn];
    float s0 = 0.f, q0 = 0.f, s1 = 0.f, q1 = 0.f;
    #pragma unroll
    for (int r = 0; r < 4; r++) {
        int row = qr + r;
        float v0 = acc0[r] + bias0;
        float v1 = acc1[r] + bias1;
        dst[(size_t)b * 2048 + row * 128 + n0 + mn] = v0;
        dst[(size_t)b * 2048 + row * 128 + n0 + 16 + mn] = v1;
        s0 += v0; q0 += v0 * v0; s1 += v1; q1 += v1 * v1;
    }
    s0 += __shfl_xor(s0, 16); s0 += __shfl_xor(s0, 32);
    q0 += __shfl_xor(q0, 16); q0 += __shfl_xor(q0, 32);
    s1 += __shfl_xor(s1, 16); s1 += __shfl_xor(s1, 32);
    q1 += __shfl_xor(q1, 16); q1 += __shfl_xor(q1, 32);
    float* so = stats_out + (b & (NREP - 1)) * 256;
    if (lane < 16) {
        atomicAdd(&so[n0 + mn], s0);
        atomicAdd(&so[128 + n0 + mn], q0);
        atomicAdd(&so[n0 + 16 + mn], s1);
        atomicAdd(&so[128 + n0 + 16 + mn], q1);
    }
}

// ---------------------------------------------------------------- nonlocal A (split-bf16 MFMA convs)
__global__ __launch_bounds__(256) void nl_a_kernel(
        const float* tsrc, const float* __restrict__ stats_in,
        const float* __restrict__ bn_g, const float* __restrict__ bn_b,
        const float* res,
        const unsigned short* __restrict__ nlwh,  // [3][64][128] hi
        const unsigned short* __restrict__ nlwl,  // lo
        const float* __restrict__ g_b, const float* __restrict__ t_b,
        const float* __restrict__ p_b, const float* __restrict__ cpw,
        const unsigned short* __restrict__ nlWh,  // [128][64] hi
        const unsigned short* __restrict__ nlWl,  // lo
        const float* __restrict__ W_b,
        const int* __restrict__ restored,
        float* hdst, float* wydst, float* __restrict__ wst) {
    __shared__ __align__(16) unsigned short xch[16][136];
    __shared__ __align__(16) unsigned short xcl[16][136];
    __shared__ float cg[3][64][17];
    __shared__ float gx[64][9];
    __shared__ float tv[16], pv[8];
    __shared__ __align__(16) unsigned short ybh[16][72];
    __shared__ __align__(16) unsigned short ybl[16][72];
    __shared__ float wyl[128][17];
    __shared__ int ro[16];
    int b = blockIdx.x, t = threadIdx.x;
    if (t < 16) ro[t] = restored[t];
    __syncthreads();
    {
        int c = t & 127;
        float mean = 0.f, inv = 0.f, bb = 0.f;
        if (stats_in) {
            float ssum, ssq;
            stats_sum(stats_in, c, ssum, ssq);
            mean = ssum * (1.f / 65536.f);
            float var = ssq * (1.f / 65536.f) - mean * mean;
            inv = rsqrtf(var + 1e-5f) * bn_g[c];
            bb = bn_b[c];
        }
        for (int idx = t; idx < 2048; idx += 256) {
            int r = idx >> 7;
            float v = tsrc[(size_t)b * 2048 + idx];
            if (stats_in) v = fmaxf((v - mean) * inv + bb, 0.f);
            if (res) v += res[(size_t)b * 2048 + idx];
            hdst[(size_t)b * 2048 + idx] = v;
            unsigned short h, l;
            splitbf(v, h, l);
            xch[ro[r]][c] = h;
            xcl[ro[r]][c] = l;
        }
    }
    __syncthreads();
    int wv = t >> 6, lane = t & 63;
    int mn = lane & 15, kq = (lane >> 4) << 3, qr = (lane >> 4) << 2;
    {
        short8 bh[4], bl[4];
        #pragma unroll
        for (int s = 0; s < 4; s++) {
            bh[s] = *(const short8*)&xch[mn][s * 32 + kq];
            bl[s] = *(const short8*)&xcl[mn][s * 32 + kq];
        }
        #pragma unroll
        for (int jj = 0; jj < 3; jj++) {
            int jb = wv + jj * 4;
            int conv = jb >> 2, mt = jb & 3;
            const unsigned short* aph = nlwh + (conv * 64 + mt * 16 + mn) * 128 + kq;
            const unsigned short* apl = nlwl + (conv * 64 + mt * 16 + mn) * 128 + kq;
            f32x4 acc = {0.f, 0.f, 0.f, 0.f};
            #pragma unroll
            for (int s = 0; s < 4; s++)
                acc = mfma_split(*(const short8*)(aph + s * 32), *(const short8*)(apl + s * 32),
                                 bh[s], bl[s], acc);
            const float* bias = conv == 0 ? g_b : conv == 1 ? t_b : p_b;
            #pragma unroll
            for (int r = 0; r < 4; r++) {
                int o = mt * 16 + qr + r;
                cg[conv][o][mn] = acc[r] + bias[o];
            }
        }
    }
    __syncthreads();
    for (int u = t; u < 512; u += 256) {
        int c = u >> 3, w2 = u & 7;
        gx[c][w2] = fmaxf(cg[0][c][2 * w2], cg[0][c][2 * w2 + 1]);
    }
    if (t < 16) {
        float s = 0.f;
        for (int c2 = 0; c2 < 64; c2++) s += cg[1][c2][t] * cpw[c2];
        tv[t] = s;
    }
    if (t >= 64 && t < 72) {
        int w2 = t - 64;
        float s = 0.f;
        for (int c2 = 0; c2 < 64; c2++)
            s += fmaxf(cg[2][c2][2 * w2], cg[2][c2][2 * w2 + 1]) * cpw[64 + c2];
        pv[w2] = s;
    }
    __syncthreads();
    for (int u = t; u < 1024; u += 256) {
        int j = u >> 6, c = u & 63;
        float s = 0.f;
        #pragma unroll
        for (int w2 = 0; w2 < 8; w2++)
            s += fmaxf(tv[j] + pv[w2], 0.f) * gx[c][w2];
        unsigned short h, l;
        splitbf(s * 0.125f, h, l);
        ybh[j][c] = h; ybl[j][c] = l;
    }
    __syncthreads();
    {
        short8 byh0 = *(const short8*)&ybh[mn][kq];
        short8 byh1 = *(const short8*)&ybh[mn][32 + kq];
        short8 byl0 = *(const short8*)&ybl[mn][kq];
        short8 byl1 = *(const short8*)&ybl[mn][32 + kq];
        #pragma unroll
        for (int mm = 0; mm < 2; mm++) {
            int mt = wv * 2 + mm;
            const unsigned short* aph = nlWh + (mt * 16 + mn) * 64 + kq;
            const unsigned short* apl = nlWl + (mt * 16 + mn) * 64 + kq;
            f32x4 acc = {0.f, 0.f, 0.f, 0.f};
            acc = mfma_split(*(const short8*)aph, *(const short8*)apl, byh0, byl0, acc);
            acc = mfma_split(*(const short8*)(aph + 32), *(const short8*)(apl + 32), byh1, byl1, acc);
            #pragma unroll
            for (int r = 0; r < 4; r++) {
                int o = mt * 16 + qr + r;
                wyl[o][mn] = acc[r] + W_b[o];
            }
        }
    }
    __syncthreads();
    {
        int c = t & 127;
        float s = 0.f, q = 0.f;
        for (int idx = t; idx < 2048; idx += 256) {
            int j = idx >> 7;
            float v = wyl[c][j];
            wydst[(size_t)b * 2048 + idx] = v;
            s += v; q += v * v;
        }
        float* red = (float*)cg;
        red[t] = s; red[256 + t] = q;
        __syncthreads();
        float* so = wst + (b & (NREP - 1)) * 256;
        if (t < 128) {
            atomicAdd(&so[t], red[t] + red[t + 128]);
            atomicAdd(&so[128 + t], red[256 + t] + red[256 + t + 128]);
        }
    }
}

// ---------------------------------------------------------------- nonlocal B (fp32, reads finalized stats)
__global__ void nl_b_kernel(const float* __restrict__ wy, const float* __restrict__ wst,
                            const float* __restrict__ g, const float* __restrict__ bta,
                            const int* __restrict__ restored, float* z) {
    size_t i4 = (size_t)blockIdx.x * 256 + threadIdx.x;
    size_t idx = i4 << 2;
    int c = (int)(idx & 127);
    int r = (int)((idx >> 7) & 15);
    size_t b = idx >> 11;
    int jg = restored[r];
    float4 w = *(const float4*)&wy[((b << 4) + jg) * 128 + c];
    float4 zo = *(const float4*)&z[idx];
    float4 sm = *(const float4*)&wst[c];
    float4 sq = *(const float4*)&wst[128 + c];
    float4 gg = *(const float4*)&g[c];
    float4 bb = *(const float4*)&bta[c];
    float4 out;
    { float m = sm.x*(1.f/65536.f); float v = sq.x*(1.f/65536.f)-m*m;
      out.x = (w.x-m)*rsqrtf(v+1e-5f)*gg.x + bb.x + zo.x; }
    { float m = sm.y*(1.f/65536.f); float v = sq.y*(1.f/65536.f)-m*m;
      out.y = (w.y-m)*rsqrtf(v+1e-5f)*gg.y + bb.y + zo.y; }
    { float m = sm.z*(1.f/65536.f); float v = sq.z*(1.f/65536.f)-m*m;
      out.z = (w.z-m)*rsqrtf(v+1e-5f)*gg.z + bb.z + zo.z; }
    { float m = sm.w*(1.f/65536.f); float v = sq.w*(1.f/65536.f)-m*m;
      out.w = (w.w-m)*rsqrtf(v+1e-5f)*gg.w + bb.w + zo.w; }
    *(float4*)&z[idx] = out;
}

// ---------------------------------------------------------------- gconv out (128->3, fp32)
__global__ __launch_bounds__(256) void gconv_out_kernel(
        const float* __restrict__ h, const float* __restrict__ W,
        const float* __restrict__ bias, const float* __restrict__ off,
        const float* __restrict__ diag, float* __restrict__ out) {
    __shared__ float hs[16][128];
    __shared__ float gsv[16][128];
    __shared__ float offs[256];
    __shared__ float p0[48][4], p1[48][4];
    int b = blockIdx.x, t = threadIdx.x;
    offs[t] = off[t];
    for (int idx = t; idx < 2048; idx += 256)
        ((float*)hs)[idx] = h[(size_t)b * 2048 + idx];
    __syncthreads();
    for (int idx = t; idx < 2048; idx += 256) {
        int i = idx >> 7, f = idx & 127;
        float g = 0.f;
        #pragma unroll
        for (int j = 0; j < 16; j++) g += offs[i * 16 + j] * hs[j][f];
        gsv[i][f] = g;
    }
    __syncthreads();
    if (t < 192) {
        int oid = t >> 2, chunk = t & 3;
        int i = oid / 3, o = oid % 3;
        float a0 = 0.f, a1 = 0.f;
        int f0 = chunk * 32;
        for (int f = f0; f < f0 + 32; f++) {
            a0 += hs[i][f] * W[f * 3 + o];
            a1 += gsv[i][f] * W[384 + f * 3 + o];
        }
        p0[oid][chunk] = a0; p1[oid][chunk] = a1;
    }
    __syncthreads();
    if (t < 48) {
        int i = t / 3, o = t % 3;
        float a0 = p0[t][0] + p0[t][1] + p0[t][2] + p0[t][3];
        float a1 = p1[t][0] + p1[t][1] + p1[t][2] + p1[t][3];
        out[(size_t)b * 48 + t] = diag[i] * a0 + a1 + bias[o];
    }
}

// ================================================================ launch
extern "C" void kernel_launch(void* const* d_in, const int* in_sizes, int n_in,
                              void* d_out, int out_size, void* d_ws, size_t ws_size,
                              hipStream_t stream) {
    (void)n_in; (void)out_size; (void)ws_size;
    const float* x        = (const float*)d_in[0];
    const float* gc_in_W  = (const float*)d_in[1];
    const float* gc_in_e  = (const float*)d_in[2];
    const float* gc_in_b  = (const float*)d_in[3];
    const float* bn_in_g  = (const float*)d_in[4];
    const float* bn_in_b  = (const float*)d_in[5];
    const float* W_res    = (const float*)d_in[6];
    const float* e_res    = (const float*)d_in[7];
    const float* b_res    = (const float*)d_in[8];
    const float* bng_res  = (const float*)d_in[9];
    const float* bnb_res  = (const float*)d_in[10];
    const float* nl_g_w   = (const float*)d_in[11];
    const float* nl_g_b   = (const float*)d_in[12];
    const float* nl_t_w   = (const float*)d_in[13];
    const float* nl_t_b   = (const float*)d_in[14];
    const float* nl_p_w   = (const float*)d_in[15];
    const float* nl_p_b   = (const float*)d_in[16];
    const float* nl_cp_w  = (const float*)d_in[17];
    const float* nl_W_w   = (const float*)d_in[18];
    const float* nl_W_b   = (const float*)d_in[19];
    const float* nl_bn_g  = (const float*)d_in[20];
    const float* nl_bn_b  = (const float*)d_in[21];
    const float* gc_out_W = (const float*)d_in[22];
    const float* gc_out_e = (const float*)d_in[23];
    const float* gc_out_b = (const float*)d_in[24];
    const int*   mask_rows = (const int*)d_in[25];
    const int*   mask_cols = (const int*)d_in[26];
    const int*   restored  = (const int*)d_in[28];
    int nnz = in_sizes[2];

    float* ws        = (float*)d_ws;
    float* off_all   = ws;                 // 0..2560
    float* diag_all  = ws + 2560;          // ..2720
    float* stats     = ws + 2720;          // 14 slots x 4096 = 57344 -> ..60064
    float* finals    = ws + 60064;         // 5 x 256 -> ..61344
    unsigned short* Wbh  = (unsigned short*)(ws + 61440);
    unsigned short* Wbl  = Wbh + WB_N;
    unsigned short* nlwh = Wbl + WB_N;
    unsigned short* nlwl = nlwh + NLW_N;
    unsigned short* nlWh = nlwl + NLW_N;
    unsigned short* nlWl = nlWh + NLWW_N;  // ends at float 61440 + 425984 = 487424
    float* Z = ws + 487424;
    float* T = Z + ELEMS;                  // total ~69.06 MB

    hipMemsetAsync(stats, 0, 14 * SLOT * sizeof(float), stream);
    adj_kernel<<<10, 16, 0, stream>>>(gc_in_e, e_res, gc_out_e, mask_rows, mask_cols,
                                      nnz, off_all, diag_all);
    prep_w_kernel<<<(WB_N + NLW_N + NLWW_N + 255) / 256, 256, 0, stream>>>(
        W_res, nl_g_w, nl_t_w, nl_p_w, nl_W_w, Wbh, Wbl, nlwh, nlwl, nlWh, nlWl);

    gconv_in_kernel<<<B, 256, 0, stream>>>(x, gc_in_W, gc_in_b, off_all, diag_all,
                                           Z, stats);
    nl_a_kernel<<<B, 256, 0, stream>>>(Z, stats, bn_in_g, bn_in_b, nullptr,
                                       nlwh, nlwl, nl_g_b, nl_t_b, nl_p_b, nl_cp_w,
                                       nlWh, nlWl, nl_W_b, restored, Z, T, stats + SLOT);
    finalize_kernel<<<1, 256, 0, stream>>>(stats + SLOT, finals);
    nl_b_kernel<<<8192, 256, 0, stream>>>(T, finals, nl_bn_g, nl_bn_b, restored, Z);

    int sl = 2;
    for (int i = 0; i < NLAYERS; i++) {
        int l0 = 2 * i, l1 = 2 * i + 1, li = i + 1;
        gconv_mfma_kernel<<<B, 256, 0, stream>>>(
            Z, nullptr, nullptr, nullptr,
            Wbh + (size_t)l0 * 32768, Wbl + (size_t)l0 * 32768, b_res + l0 * 128,
            off_all + (1 + l0) * 256, diag_all + (1 + l0) * 16, T,
            stats + (size_t)sl * SLOT);
        gconv_mfma_kernel<<<B, 256, 0, stream>>>(
            T, stats + (size_t)sl * SLOT, bng_res + l0 * 128, bnb_res + l0 * 128,
            Wbh + (size_t)l1 * 32768, Wbl + (size_t)l1 * 32768, b_res + l1 * 128,
            off_all + (1 + l1) * 256, diag_all + (1 + l1) * 16, T,
            stats + (size_t)(sl + 1) * SLOT);
        nl_a_kernel<<<B, 256, 0, stream>>>(
            T, stats + (size_t)(sl + 1) * SLOT, bng_res + l1 * 128, bnb_res + l1 * 128, Z,
            nlwh + li * 24576, nlwl + li * 24576,
            nl_g_b + li * 64, nl_t_b + li * 64, nl_p_b + li * 64,
            nl_cp_w + li * 128, nlWh + li * 8192, nlWl + li * 8192, nl_W_b + li * 128,
            restored, Z, T, stats + (size_t)(sl + 2) * SLOT);
        finalize_kernel<<<1, 256, 0, stream>>>(stats + (size_t)(sl + 2) * SLOT,
                                               finals + li * 256);
        nl_b_kernel<<<8192, 256, 0, stream>>>(T, finals + li * 256,
                                              nl_bn_g + li * 128, nl_bn_b + li * 128,
                                              restored, Z);
        sl += 3;
    }
    gconv_out_kernel<<<B, 256, 0, stream>>>(Z, gc_out_W, gc_out_b,
                                            off_all + 9 * 256, diag_all + 9 * 16,
                                            (float*)d_out);
}

// Round 5
// 1231.072 us; speedup vs baseline: 1.8631x; 1.0476x over previous
//
#include <hip/hip_runtime.h>

#define B 4096
#define J 16
#define HID 128
#define INTER 64
#define NLAYERS 4
#define NEGV -9000000000000000.0f
#define ELEMS ((size_t)B*16*128)
#define NREP 16          // stats replicas (atomic spread)
#define SLOT 4096        // floats per stats slot = NREP*256

typedef __attribute__((ext_vector_type(8))) short short8;
typedef __attribute__((ext_vector_type(4))) float f32x4;

static __device__ __forceinline__ unsigned short f2bf(float x) {
    unsigned u = __float_as_uint(x);
    unsigned r = u + 0x7fffu + ((u >> 16) & 1u);
    return (unsigned short)(r >> 16);
}
static __device__ __forceinline__ void splitbf(float x, unsigned short& h, unsigned short& l) {
    h = f2bf(x);
    float hf = __uint_as_float((unsigned)h << 16);
    l = f2bf(x - hf);
}
static __device__ __forceinline__ f32x4 mfma16(short8 a, short8 b, f32x4 c) {
    return __builtin_amdgcn_mfma_f32_16x16x32_bf16(a, b, c, 0, 0, 0);
}
static __device__ __forceinline__ f32x4 mfma_split(short8 ah, short8 al,
                                                   short8 bh, short8 bl, f32x4 acc) {
    acc = mfma16(ah, bh, acc);
    acc = mfma16(ah, bl, acc);
    acc = mfma16(al, bh, acc);
    return acc;
}
static __device__ __forceinline__ void stats_sum(const float* __restrict__ slot, int c,
                                                 float& s, float& q) {
    s = 0.f; q = 0.f;
    #pragma unroll
    for (int r = 0; r < NREP; r++) {
        s += slot[r * 256 + c];
        q += slot[r * 256 + 128 + c];
    }
}
static __device__ __forceinline__ float bfpair(unsigned short h, unsigned short l) {
    return __uint_as_float((unsigned)h << 16) + __uint_as_float((unsigned)l << 16);
}

// ---------------------------------------------------------------- adjacency
__global__ void adj_kernel(const float* __restrict__ e_in,
                           const float* __restrict__ e_res,
                           const float* __restrict__ e_out,
                           const int* __restrict__ rows,
                           const int* __restrict__ cols, int nnz,
                           float* __restrict__ off_all,
                           float* __restrict__ diag_all) {
    int m = blockIdx.x;
    int i = threadIdx.x;
    const float* e = (m == 0) ? e_in : (m <= 8) ? e_res + (size_t)(m - 1) * nnz : e_out;
    float l[16];
    for (int j = 0; j < 16; j++) l[j] = NEGV;
    for (int k = 0; k < nnz; k++)
        if (rows[k] == i) l[cols[k]] = e[k];
    float mx = l[0];
    for (int j = 1; j < 16; j++) mx = fmaxf(mx, l[j]);
    float ex[16], s = 0.f;
    for (int j = 0; j < 16; j++) { ex[j] = expf(l[j] - mx); s += ex[j]; }
    float inv = 1.f / s;
    for (int j = 0; j < 16; j++) {
        float a = ex[j] * inv;
        if (j == i) { diag_all[m * 16 + i] = a; a = 0.f; }
        off_all[m * 256 + i * 16 + j] = a;
    }
}

// ---------------------------------------------------------------- weight prep
#define WB_N   262144     // 8 * 128 * 256
#define NLW_N  122880     // 5 * 3 * 64 * 128
#define NLWW_N 40960      // 5 * 128 * 64
__global__ void prep_w_kernel(const float* __restrict__ W_res,
                              const float* __restrict__ g_w, const float* __restrict__ t_w,
                              const float* __restrict__ p_w, const float* __restrict__ W_w,
                              unsigned short* __restrict__ Wbh, unsigned short* __restrict__ Wbl,
                              unsigned short* __restrict__ nlwh, unsigned short* __restrict__ nlwl,
                              unsigned short* __restrict__ nlWh, unsigned short* __restrict__ nlWl) {
    int i = blockIdx.x * 256 + threadIdx.x;
    unsigned short h, l;
    if (i < WB_N) {
        int lay = i >> 15, rem = i & 32767, n = rem >> 8, k = rem & 255;
        int d = k >> 7, f = k & 127;
        splitbf(W_res[(((lay << 1) | d) * 128 + f) * 128 + n], h, l);
        Wbh[i] = h; Wbl[i] = l;
    } else if (i < WB_N + NLW_N) {
        int j = i - WB_N;
        int lay = j / 24576, r2 = j % 24576;
        int conv = r2 >> 13, oc = r2 & 8191;
        const float* src = conv == 0 ? g_w : conv == 1 ? t_w : p_w;
        splitbf(src[lay * 8192 + oc], h, l);
        nlwh[j] = h; nlwl[j] = l;
    } else if (i < WB_N + NLW_N + NLWW_N) {
        int j = i - WB_N - NLW_N;
        splitbf(W_w[j], h, l);
        nlWh[j] = h; nlWl[j] = l;
    }
}

// vt[l][c] = sum_c2 cp_w[l][c2] * t_w[l][c2][c];  ct[l] = cp_w[l][:64] . t_b[l]
__global__ void prep_vt_kernel(const float* __restrict__ t_w, const float* __restrict__ t_b,
                               const float* __restrict__ cp_w,
                               float* __restrict__ vt, float* __restrict__ ct) {
    int l = blockIdx.x, c = threadIdx.x;
    float s = 0.f;
    for (int c2 = 0; c2 < 64; c2++)
        s += cp_w[l * 128 + c2] * t_w[(l * 64 + c2) * 128 + c];
    vt[l * 128 + c] = s;
    if (c == 0) {
        float s2 = 0.f;
        for (int c2 = 0; c2 < 64; c2++) s2 += cp_w[l * 128 + c2] * t_b[l * 64 + c2];
        ct[l] = s2;
    }
}

// ---------------------------------------------------------------- gconv in (F=2), fused stats
__global__ __launch_bounds__(256) void gconv_in_kernel(
        const float* __restrict__ x, const float* __restrict__ W,
        const float* __restrict__ bias, const float* __restrict__ off,
        const float* __restrict__ diag, float* __restrict__ out,
        float* __restrict__ stats_out) {
    __shared__ float xs[16][2];
    __shared__ float gs[16][2];
    __shared__ float red[512];
    int b = blockIdx.x, t = threadIdx.x;
    if (t < 32) xs[t >> 1][t & 1] = x[b * 32 + t];
    __syncthreads();
    if (t < 32) {
        int i = t >> 1, f = t & 1;
        float g = 0.f;
        #pragma unroll
        for (int j = 0; j < 16; j++) g += off[i * 16 + j] * xs[j][f];
        gs[i][f] = g;
    }
    __syncthreads();
    int o = t & 127;
    float w00 = W[o], w01 = W[128 + o], w10 = W[256 + o], w11 = W[384 + o], bo = bias[o];
    float s = 0.f, q = 0.f;
    for (int idx = t; idx < 2048; idx += 256) {
        int i = idx >> 7;
        float v = diag[i] * (xs[i][0] * w00 + xs[i][1] * w01)
                + gs[i][0] * w10 + gs[i][1] * w11 + bo;
        out[(size_t)b * 2048 + idx] = v;
        s += v; q += v * v;
    }
    red[t] = s; red[256 + t] = q;
    __syncthreads();
    float* so = stats_out + (b & (NREP - 1)) * 256;
    if (t < 128) {
        atomicAdd(&so[t], red[t] + red[t + 128]);
        atomicAdd(&so[128 + t], red[256 + t] + red[256 + t + 128]);
    }
}

// ---------------------------------------------------------------- gconv 128->128 (split-bf16 MFMA)
// wy == null: h = src, optionally bn+relu via stats_in.
// wy != null: fused nl_b: h = bn_wy(wy[b, restored[r], :]) + src; z written to zdst.
__global__ __launch_bounds__(256) void gconv_mfma_kernel(
        const float* src, const float* wy,
        const float* __restrict__ stats_in,
        const float* __restrict__ bn_g, const float* __restrict__ bn_b,
        const int* __restrict__ restored, float* zdst,
        const unsigned short* __restrict__ Wbh,
        const unsigned short* __restrict__ Wbl,
        const float* __restrict__ bias,
        const float* __restrict__ off, const float* __restrict__ diag,
        float* dst, float* __restrict__ stats_out) {
    __shared__ float hraw[16][132];
    __shared__ __align__(16) unsigned short ksh[16][264];
    __shared__ __align__(16) unsigned short ksl[16][264];
    __shared__ float offs[256];
    __shared__ float diags[16];
    int b = blockIdx.x, t = threadIdx.x;
    offs[t] = off[t];
    if (t < 16) diags[t] = diag[t];
    {
        int c = t & 127;
        float mean = 0.f, inv = 0.f, bb = 0.f;
        if (stats_in) {
            float ssum, ssq;
            stats_sum(stats_in, c, ssum, ssq);
            mean = ssum * (1.f / 65536.f);
            float var = ssq * (1.f / 65536.f) - mean * mean;
            inv = rsqrtf(var + 1e-5f) * bn_g[c];
            bb = bn_b[c];
        }
        for (int idx = t; idx < 2048; idx += 256) {
            int r = idx >> 7;
            float v;
            if (wy) {
                float wval = wy[(size_t)b * 2048 + restored[r] * 128 + c];
                v = (wval - mean) * inv + bb + src[(size_t)b * 2048 + idx];
                zdst[(size_t)b * 2048 + idx] = v;
            } else {
                v = src[(size_t)b * 2048 + idx];
                if (stats_in) v = fmaxf((v - mean) * inv + bb, 0.f);
            }
            hraw[r][c] = v;
        }
    }
    __syncthreads();
    for (int u = t; u < 512; u += 256) {
        int i = u >> 5, f4 = (u & 31) << 2;
        float4 hv = *(const float4*)&hraw[i][f4];
        float4 g = make_float4(0.f, 0.f, 0.f, 0.f);
        #pragma unroll
        for (int j = 0; j < 16; j++) {
            float w = offs[i * 16 + j];
            float4 hj = *(const float4*)&hraw[j][f4];
            g.x += w * hj.x; g.y += w * hj.y; g.z += w * hj.z; g.w += w * hj.w;
        }
        float d = diags[i];
        unsigned short h0,l0,h1,l1,h2,l2,h3,l3;
        splitbf(d * hv.x, h0, l0); splitbf(d * hv.y, h1, l1);
        splitbf(d * hv.z, h2, l2); splitbf(d * hv.w, h3, l3);
        *(uint2*)&ksh[i][f4] = make_uint2((unsigned)h0 | ((unsigned)h1 << 16),
                                          (unsigned)h2 | ((unsigned)h3 << 16));
        *(uint2*)&ksl[i][f4] = make_uint2((unsigned)l0 | ((unsigned)l1 << 16),
                                          (unsigned)l2 | ((unsigned)l3 << 16));
        splitbf(g.x, h0, l0); splitbf(g.y, h1, l1);
        splitbf(g.z, h2, l2); splitbf(g.w, h3, l3);
        *(uint2*)&ksh[i][128 + f4] = make_uint2((unsigned)h0 | ((unsigned)h1 << 16),
                                                (unsigned)h2 | ((unsigned)h3 << 16));
        *(uint2*)&ksl[i][128 + f4] = make_uint2((unsigned)l0 | ((unsigned)l1 << 16),
                                                (unsigned)l2 | ((unsigned)l3 << 16));
    }
    __syncthreads();
    int wv = t >> 6, lane = t & 63;
    int mn = lane & 15, kq = (lane >> 4) << 3, qr = (lane >> 4) << 2;
    int n0 = wv << 5;
    f32x4 acc0 = {0.f, 0.f, 0.f, 0.f}, acc1 = {0.f, 0.f, 0.f, 0.f};
    const unsigned short* wh0 = Wbh + (size_t)(n0 + mn) * 256 + kq;
    const unsigned short* wl0 = Wbl + (size_t)(n0 + mn) * 256 + kq;
    #pragma unroll
    for (int s = 0; s < 8; s++) {
        int k0 = s << 5;
        short8 ah = *(const short8*)&ksh[mn][k0 + kq];
        short8 al = *(const short8*)&ksl[mn][k0 + kq];
        acc0 = mfma_split(ah, al, *(const short8*)(wh0 + k0), *(const short8*)(wl0 + k0), acc0);
        acc1 = mfma_split(ah, al, *(const short8*)(wh0 + 4096 + k0), *(const short8*)(wl0 + 4096 + k0), acc1);
    }
    float bias0 = bias[n0 + mn], bias1 = bias[n0 + 16 + mn];
    float s0 = 0.f, q0 = 0.f, s1 = 0.f, q1 = 0.f;
    #pragma unroll
    for (int r = 0; r < 4; r++) {
        int row = qr + r;
        float v0 = acc0[r] + bias0;
        float v1 = acc1[r] + bias1;
        dst[(size_t)b * 2048 + row * 128 + n0 + mn] = v0;
        dst[(size_t)b * 2048 + row * 128 + n0 + 16 + mn] = v1;
        s0 += v0; q0 += v0 * v0; s1 += v1; q1 += v1 * v1;
    }
    s0 += __shfl_xor(s0, 16); s0 += __shfl_xor(s0, 32);
    q0 += __shfl_xor(q0, 16); q0 += __shfl_xor(q0, 32);
    s1 += __shfl_xor(s1, 16); s1 += __shfl_xor(s1, 32);
    q1 += __shfl_xor(q1, 16); q1 += __shfl_xor(q1, 32);
    float* so = stats_out + (b & (NREP - 1)) * 256;
    if (lane < 16) {
        atomicAdd(&so[n0 + mn], s0);
        atomicAdd(&so[128 + n0 + mn], q0);
        atomicAdd(&so[n0 + 16 + mn], s1);
        atomicAdd(&so[128 + n0 + 16 + mn], q1);
    }
}

// ---------------------------------------------------------------- nonlocal A
// t-conv folded into vt/ct. g-conv & p-conv via MFMA. wyl unioned into cgbuf.
#define CG(conv, o, j) cgbuf[((conv) * 64 + (o)) * 17 + (j)]
#define WYL(o, j)      cgbuf[(o) * 17 + (j)]
__global__ __launch_bounds__(256) void nl_a_kernel(
        const float* tsrc, const float* __restrict__ stats_in,
        const float* __restrict__ bn_g, const float* __restrict__ bn_b,
        const float* res,
        const unsigned short* __restrict__ nlwh,  // [3][64][128] hi (g@0, p@2)
        const unsigned short* __restrict__ nlwl,
        const float* __restrict__ g_b, const float* __restrict__ p_b,
        const float* __restrict__ cpw,
        const float* __restrict__ vt, const float* __restrict__ ctp,
        const unsigned short* __restrict__ nlWh,  // [128][64] hi
        const unsigned short* __restrict__ nlWl,
        const float* __restrict__ W_b,
        const int* __restrict__ restored,
        float* hdst, float* wydst, float* __restrict__ wst) {
    __shared__ __align__(16) unsigned short xch[16][136];
    __shared__ __align__(16) unsigned short xcl[16][136];
    __shared__ float cgbuf[2176];          // cg[2][64][17] ∪ wyl[128][17]
    __shared__ float gx[64][9];            // also reused as red[512] in epilogue
    __shared__ float tvp[16][4], pvp[8][8];
    __shared__ float tv[16], pv[8];
    __shared__ float vtl[128];
    __shared__ __align__(16) unsigned short ybh[16][72];
    __shared__ __align__(16) unsigned short ybl[16][72];
    int b = blockIdx.x, t = threadIdx.x;
    // -------- phase 0: load + bn/relu + residual, split to LDS (grouped rows)
    {
        int c = t & 127;
        if (t < 128) vtl[t] = vt[t];
        float mean = 0.f, inv = 0.f, bb = 0.f;
        {
            float ssum, ssq;
            stats_sum(stats_in, c, ssum, ssq);
            mean = ssum * (1.f / 65536.f);
            float var = ssq * (1.f / 65536.f) - mean * mean;
            inv = rsqrtf(var + 1e-5f) * bn_g[c];
            bb = bn_b[c];
        }
        for (int idx = t; idx < 2048; idx += 256) {
            int r = idx >> 7;
            float v = tsrc[(size_t)b * 2048 + idx];
            v = fmaxf((v - mean) * inv + bb, 0.f);
            if (res) v += res[(size_t)b * 2048 + idx];
            hdst[(size_t)b * 2048 + idx] = v;
            unsigned short h, l;
            splitbf(v, h, l);
            int rg = restored[r];
            xch[rg][c] = h;
            xcl[rg][c] = l;
        }
    }
    __syncthreads();
    int wv = t >> 6, lane = t & 63;
    int mn = lane & 15, kq = (lane >> 4) << 3, qr = (lane >> 4) << 2;
    // -------- phase 1: g-conv + p-conv MFMA (8 tiles over 4 waves x 2)
    {
        short8 bh[4], bl[4];
        #pragma unroll
        for (int s = 0; s < 4; s++) {
            bh[s] = *(const short8*)&xch[mn][s * 32 + kq];
            bl[s] = *(const short8*)&xcl[mn][s * 32 + kq];
        }
        #pragma unroll
        for (int jj = 0; jj < 2; jj++) {
            int jb = wv + jj * 4;          // 0..7
            int conv = jb >> 2;            // 0=g, 1=p
            int mt = jb & 3;
            int wbase = (conv == 0) ? 0 : 128;   // g at block 0, p at block 2 (2*64=128 rows)
            const unsigned short* aph = nlwh + (size_t)(wbase + mt * 16 + mn) * 128 + kq;
            const unsigned short* apl = nlwl + (size_t)(wbase + mt * 16 + mn) * 128 + kq;
            f32x4 acc = {0.f, 0.f, 0.f, 0.f};
            #pragma unroll
            for (int s = 0; s < 4; s++)
                acc = mfma_split(*(const short8*)(aph + s * 32), *(const short8*)(apl + s * 32),
                                 bh[s], bl[s], acc);
            const float* bias = (conv == 0) ? g_b : p_b;
            #pragma unroll
            for (int r = 0; r < 4; r++) {
                int o = mt * 16 + qr + r;
                CG(conv, o, mn) = acc[r] + bias[o];
            }
        }
    }
    __syncthreads();
    // -------- phase 2: gx pool (t<128), pv partials (128<=t<192), tv partials (t>=192)
    if (t < 128) {
        for (int u = t; u < 512; u += 128) {
            int c = u >> 3, w2 = u & 7;
            gx[c][w2] = fmaxf(CG(0, c, 2 * w2), CG(0, c, 2 * w2 + 1));
        }
    } else if (t < 192) {
        int u = t - 128, w2 = u & 7, ch = u >> 3;   // ch in [0,8)
        float s = 0.f;
        for (int c = ch * 8; c < ch * 8 + 8; c++)
            s += fmaxf(CG(1, c, 2 * w2), CG(1, c, 2 * w2 + 1)) * cpw[64 + c];
        pvp[w2][ch] = s;
    } else {
        int u = t - 192, j = u & 15, ch = u >> 4;   // ch in [0,4)
        float s = 0.f;
        int c0 = ch * 32;
        for (int c = c0; c < c0 + 32; c += 2) {
            unsigned hh = *(const unsigned*)&xch[j][c];
            unsigned ll = *(const unsigned*)&xcl[j][c];
            float v0 = bfpair((unsigned short)hh, (unsigned short)ll);
            float v1 = bfpair((unsigned short)(hh >> 16), (unsigned short)(ll >> 16));
            s += vtl[c] * v0 + vtl[c + 1] * v1;
        }
        tvp[j][ch] = s;
    }
    __syncthreads();
    // -------- phase 3: finalize tv/pv
    if (t < 16) {
        tv[t] = tvp[t][0] + tvp[t][1] + tvp[t][2] + tvp[t][3] + ctp[0];
    } else if (t < 24) {
        int w2 = t - 16;
        float s = 0.f;
        #pragma unroll
        for (int ch = 0; ch < 8; ch++) s += pvp[w2][ch];
        pv[w2] = s;
    }
    __syncthreads();
    // -------- phase 4: y = f @ gx^T, split
    for (int u = t; u < 1024; u += 256) {
        int j = u >> 6, c = u & 63;
        float s = 0.f;
        #pragma unroll
        for (int w2 = 0; w2 < 8; w2++)
            s += fmaxf(tv[j] + pv[w2], 0.f) * gx[c][w2];
        unsigned short h, l;
        splitbf(s * 0.125f, h, l);
        ybh[j][c] = h; ybl[j][c] = l;
    }
    __syncthreads();
    // -------- phase 5: Wy MFMA (overwrites cgbuf as wyl)
    {
        short8 byh0 = *(const short8*)&ybh[mn][kq];
        short8 byh1 = *(const short8*)&ybh[mn][32 + kq];
        short8 byl0 = *(const short8*)&ybl[mn][kq];
        short8 byl1 = *(const short8*)&ybl[mn][32 + kq];
        #pragma unroll
        for (int mm = 0; mm < 2; mm++) {
            int mt = wv * 2 + mm;
            const unsigned short* aph = nlWh + (size_t)(mt * 16 + mn) * 64 + kq;
            const unsigned short* apl = nlWl + (size_t)(mt * 16 + mn) * 64 + kq;
            f32x4 acc = {0.f, 0.f, 0.f, 0.f};
            acc = mfma_split(*(const short8*)aph, *(const short8*)apl, byh0, byl0, acc);
            acc = mfma_split(*(const short8*)(aph + 32), *(const short8*)(apl + 32), byh1, byl1, acc);
            #pragma unroll
            for (int r = 0; r < 4; r++) {
                int o = mt * 16 + qr + r;
                WYL(o, mn) = acc[r] + W_b[o];
            }
        }
    }
    __syncthreads();
    // -------- phase 6: write wy + spread stats
    {
        int c = t & 127;
        float s = 0.f, q = 0.f;
        for (int idx = t; idx < 2048; idx += 256) {
            int j = idx >> 7;
            float v = WYL(c, j);
            wydst[(size_t)b * 2048 + idx] = v;
            s += v; q += v * v;
        }
        float* red = &gx[0][0];
        red[t] = s; red[256 + t] = q;
        __syncthreads();
        float* so = wst + (b & (NREP - 1)) * 256;
        if (t < 128) {
            atomicAdd(&so[t], red[t] + red[t + 128]);
            atomicAdd(&so[128 + t], red[256 + t] + red[256 + t + 128]);
        }
    }
}

// ---------------------------------------------------------------- gconv out (128->3), fused nl_b
__global__ __launch_bounds__(256) void gconv_out_kernel(
        const float* __restrict__ h, const float* __restrict__ wy,
        const float* __restrict__ wyst,
        const float* __restrict__ nlg, const float* __restrict__ nlb,
        const int* __restrict__ restored,
        const float* __restrict__ W,
        const float* __restrict__ bias, const float* __restrict__ off,
        const float* __restrict__ diag, float* __restrict__ out) {
    __shared__ float hs[16][132];
    __shared__ float gsv[16][132];
    __shared__ float offs[256];
    __shared__ float p0[48][4], p1[48][4];
    int b = blockIdx.x, t = threadIdx.x;
    offs[t] = off[t];
    {
        int c = t & 127;
        float ssum, ssq;
        stats_sum(wyst, c, ssum, ssq);
        float mean = ssum * (1.f / 65536.f);
        float var = ssq * (1.f / 65536.f) - mean * mean;
        float inv = rsqrtf(var + 1e-5f) * nlg[c];
        float bb = nlb[c];
        for (int idx = t; idx < 2048; idx += 256) {
            int r = idx >> 7;
            float wval = wy[(size_t)b * 2048 + restored[r] * 128 + c];
            hs[r][c] = (wval - mean) * inv + bb + h[(size_t)b * 2048 + idx];
        }
    }
    __syncthreads();
    for (int idx = t; idx < 2048; idx += 256) {
        int i = idx >> 7, f = idx & 127;
        float g = 0.f;
        #pragma unroll
        for (int j = 0; j < 16; j++) g += offs[i * 16 + j] * hs[j][f];
        gsv[i][f] = g;
    }
    __syncthreads();
    if (t < 192) {
        int oid = t >> 2, chunk = t & 3;
        int i = oid / 3, o = oid % 3;
        float a0 = 0.f, a1 = 0.f;
        int f0 = chunk * 32;
        for (int f = f0; f < f0 + 32; f++) {
            a0 += hs[i][f] * W[f * 3 + o];
            a1 += gsv[i][f] * W[384 + f * 3 + o];
        }
        p0[oid][chunk] = a0; p1[oid][chunk] = a1;
    }
    __syncthreads();
    if (t < 48) {
        int i = t / 3, o = t % 3;
        float a0 = p0[t][0] + p0[t][1] + p0[t][2] + p0[t][3];
        float a1 = p1[t][0] + p1[t][1] + p1[t][2] + p1[t][3];
        out[(size_t)b * 48 + t] = diag[i] * a0 + a1 + bias[o];
    }
}

// ================================================================ launch
extern "C" void kernel_launch(void* const* d_in, const int* in_sizes, int n_in,
                              void* d_out, int out_size, void* d_ws, size_t ws_size,
                              hipStream_t stream) {
    (void)n_in; (void)out_size; (void)ws_size;
    const float* x        = (const float*)d_in[0];
    const float* gc_in_W  = (const float*)d_in[1];
    const float* gc_in_e  = (const float*)d_in[2];
    const float* gc_in_b  = (const float*)d_in[3];
    const float* bn_in_g  = (const float*)d_in[4];
    const float* bn_in_b  = (const float*)d_in[5];
    const float* W_res    = (const float*)d_in[6];
    const float* e_res    = (const float*)d_in[7];
    const float* b_res    = (const float*)d_in[8];
    const float* bng_res  = (const float*)d_in[9];
    const float* bnb_res  = (const float*)d_in[10];
    const float* nl_g_w   = (const float*)d_in[11];
    const float* nl_g_b   = (const float*)d_in[12];
    const float* nl_t_w   = (const float*)d_in[13];
    const float* nl_t_b   = (const float*)d_in[14];
    const float* nl_p_w   = (const float*)d_in[15];
    const float* nl_p_b   = (const float*)d_in[16];
    const float* nl_cp_w  = (const float*)d_in[17];
    const float* nl_W_w   = (const float*)d_in[18];
    const float* nl_W_b   = (const float*)d_in[19];
    const float* nl_bn_g  = (const float*)d_in[20];
    const float* nl_bn_b  = (const float*)d_in[21];
    const float* gc_out_W = (const float*)d_in[22];
    const float* gc_out_e = (const float*)d_in[23];
    const float* gc_out_b = (const float*)d_in[24];
    const int*   mask_rows = (const int*)d_in[25];
    const int*   mask_cols = (const int*)d_in[26];
    const int*   restored  = (const int*)d_in[28];
    int nnz = in_sizes[2];

    float* ws        = (float*)d_ws;
    float* off_all   = ws;                 // 0..2560
    float* diag_all  = ws + 2560;          // ..2720
    float* stats     = ws + 2720;          // 14 x 4096 -> ..60064
    float* vt        = ws + 60064;         // 5 x 128 -> ..60704
    float* ct        = ws + 60704;         // 5 -> ..60709
    unsigned short* Wbh  = (unsigned short*)(ws + 61440);
    unsigned short* Wbl  = Wbh + WB_N;
    unsigned short* nlwh = Wbl + WB_N;
    unsigned short* nlwl = nlwh + NLW_N;
    unsigned short* nlWh = nlwl + NLW_N;
    unsigned short* nlWl = nlWh + NLWW_N;  // ends at float 487424
    float* Z = ws + 487424;
    float* T = Z + ELEMS;

    hipMemsetAsync(stats, 0, 14 * SLOT * sizeof(float), stream);
    adj_kernel<<<10, 16, 0, stream>>>(gc_in_e, e_res, gc_out_e, mask_rows, mask_cols,
                                      nnz, off_all, diag_all);
    prep_w_kernel<<<(WB_N + NLW_N + NLWW_N + 255) / 256, 256, 0, stream>>>(
        W_res, nl_g_w, nl_t_w, nl_p_w, nl_W_w, Wbh, Wbl, nlwh, nlwl, nlWh, nlWl);
    prep_vt_kernel<<<5, 128, 0, stream>>>(nl_t_w, nl_t_b, nl_cp_w, vt, ct);

    // t0 -> T, stats s0
    gconv_in_kernel<<<B, 256, 0, stream>>>(x, gc_in_W, gc_in_b, off_all, diag_all,
                                           T, stats);
    // nonlocal 0: h0 = relu(bn(t0)) -> Z; wy -> T (stats s1)
    nl_a_kernel<<<B, 256, 0, stream>>>(T, stats, bn_in_g, bn_in_b, nullptr,
                                       nlwh, nlwl, nl_g_b, nl_p_b, nl_cp_w,
                                       vt, ct, nlWh, nlWl, nl_W_b, restored,
                                       Z, T, stats + SLOT);

    int sl = 1;   // wy-stats slot for current nonlocal
    for (int i = 0; i < NLAYERS; i++) {
        int l0 = 2 * i, l1 = 2 * i + 1, li = i + 1;
        // gconv1 + fused nl_b: z = bn(wy)+h -> Z; t1 -> T, stats sl+1
        gconv_mfma_kernel<<<B, 256, 0, stream>>>(
            Z, T, stats + (size_t)sl * SLOT,
            nl_bn_g + i * 128, nl_bn_b + i * 128, restored, Z,
            Wbh + (size_t)l0 * 32768, Wbl + (size_t)l0 * 32768, b_res + l0 * 128,
            off_all + (1 + l0) * 256, diag_all + (1 + l0) * 16, T,
            stats + (size_t)(sl + 1) * SLOT);
        // gconv2: t2 = gconv(relu(bn(t1))) -> T, stats sl+2
        gconv_mfma_kernel<<<B, 256, 0, stream>>>(
            T, nullptr, stats + (size_t)(sl + 1) * SLOT,
            bng_res + l0 * 128, bnb_res + l0 * 128, nullptr, nullptr,
            Wbh + (size_t)l1 * 32768, Wbl + (size_t)l1 * 32768, b_res + l1 * 128,
            off_all + (1 + l1) * 256, diag_all + (1 + l1) * 16, T,
            stats + (size_t)(sl + 2) * SLOT);
        // nl_a: h = relu(bn(t2)) + z -> Z; wy -> T, stats sl+3
        nl_a_kernel<<<B, 256, 0, stream>>>(
            T, stats + (size_t)(sl + 2) * SLOT,
            bng_res + l1 * 128, bnb_res + l1 * 128, Z,
            nlwh + li * 24576, nlwl + li * 24576,
            nl_g_b + li * 64, nl_p_b + li * 64, nl_cp_w + li * 128,
            vt + li * 128, ct + li, nlWh + li * 8192, nlWl + li * 8192,
            nl_W_b + li * 128, restored, Z, T, stats + (size_t)(sl + 3) * SLOT);
        sl += 3;
    }
    // gconv_out + fused nl_b (z computed on load)
    gconv_out_kernel<<<B, 256, 0, stream>>>(Z, T, stats + (size_t)sl * SLOT,
                                            nl_bn_g + NLAYERS * 128, nl_bn_b + NLAYERS * 128,
                                            restored, gc_out_W, gc_out_b,
                                            off_all + 9 * 256, diag_all + 9 * 16,
                                            (float*)d_out);
}